// Round 9
// baseline (2507.641 us; speedup 1.0000x reference)
//
#include <hip/hip_runtime.h>
#include <math.h>

#define B_ 2
#define L_ 1024
#define DM 256
#define NL_ 6
#define DI_ 512
#define DS_ 16
#define DC_ 4
#define NC_ 10
#define ALPHA_ 0.1f
#define LC 32
#define NCH (L_/LC)            // 32 chunks
#define NCHAIN (B_*DI_*DS_)    // 16384 chains
#define BETA_LC 0.034336838202925124f  // 0.9^32

typedef unsigned short ushort_t;
typedef __attribute__((ext_vector_type(8))) short s16x8;      // 8 bf16 (MFMA A/B frag)
typedef __attribute__((ext_vector_type(4))) float f32x4;      // MFMA C/D frag
typedef __attribute__((ext_vector_type(8))) unsigned short u16x8;

__device__ __forceinline__ float sigmoidf_(float x){ return 1.f/(1.f+__expf(-x)); }
__device__ __forceinline__ ushort_t f2bf(float f){
  union{float f;unsigned u;} c; c.f=f; unsigned u=c.u;
  return (ushort_t)((u + 0x7fffu + ((u>>16)&1u))>>16);
}
__device__ __forceinline__ float bf2f(ushort_t h){
  union{unsigned u;float f;} c; c.u = ((unsigned)h)<<16; return c.f;
}
// stagger-pad index for sx: insert 4-word gap every 128 words (bank-conflict fix)
__device__ __forceinline__ int kidx(int d){ return d + ((d>>7)<<2); }

// ---------------- embed ----------------
__global__ void k_embed(const float* __restrict__ emb, const float* __restrict__ pos,
                        const int* __restrict__ ids, float* __restrict__ h){
  int row = blockIdx.x;
  int t = row & (L_-1);
  int d = threadIdx.x;
  int v = ids[row];
  h[(size_t)row*DM + d] = emb[(size_t)v*DM + d] + pos[(size_t)t*DM + d];
}

// ---------------- fp32 -> bf16 weight conversion ----------------
__global__ void k_cvt2(const float* __restrict__ a, int na, const float* __restrict__ b2,
                       ushort_t* __restrict__ oa, ushort_t* __restrict__ ob, int ntot){
  int i = (blockIdx.x*256 + threadIdx.x)*4;
  if (i >= ntot) return;
  const float* src; ushort_t* dst; int k;
  if (i < na){ src = a; dst = oa; k = i; }
  else       { src = b2; dst = ob; k = i - na; }
  float4 v = *reinterpret_cast<const float4*>(&src[k]);
  ushort4 r;
  r.x = f2bf(v.x); r.y = f2bf(v.y); r.z = f2bf(v.z); r.w = f2bf(v.w);
  *reinterpret_cast<ushort4*>(&dst[k]) = r;
}

// ---------------- fused LN + in_proj GEMM (bf16 MFMA), writes xz bf16 ----------------
__global__ __launch_bounds__(256) void k_gemm_ln(const float* __restrict__ h,
    const ushort_t* __restrict__ W, const float* __restrict__ lw,
    const float* __restrict__ lb, ushort_t* __restrict__ xzb){
  __shared__ ushort_t As[64][264];
  __shared__ ushort_t Ws[64][264];
  int bm = blockIdx.y<<6, bn = blockIdx.x<<6;
  int tid = threadIdx.x;
  {
    int r = tid>>2, q = tid&3;
    const float* src = &h[(size_t)(bm+r)*DM + q*64];
    float4 v[16]; float s1=0.f, s2=0.f;
    #pragma unroll
    for (int i=0;i<16;i++){
      v[i] = *reinterpret_cast<const float4*>(src + i*4);
      s1 += v[i].x+v[i].y+v[i].z+v[i].w;
      s2 += v[i].x*v[i].x+v[i].y*v[i].y+v[i].z*v[i].z+v[i].w*v[i].w;
    }
    s1 += __shfl_xor(s1,1); s2 += __shfl_xor(s2,1);
    s1 += __shfl_xor(s1,2); s2 += __shfl_xor(s2,2);
    float mean = s1*(1.f/DM);
    float rstd = rsqrtf(s2*(1.f/DM) - mean*mean + 1e-5f);
    #pragma unroll
    for (int i=0;i<16;i++){
      int c = q*64 + i*4;
      ushort4 o;
      o.x = f2bf((v[i].x-mean)*rstd*lw[c+0]+lb[c+0]);
      o.y = f2bf((v[i].y-mean)*rstd*lw[c+1]+lb[c+1]);
      o.z = f2bf((v[i].z-mean)*rstd*lw[c+2]+lb[c+2]);
      o.w = f2bf((v[i].w-mean)*rstd*lw[c+3]+lb[c+3]);
      *reinterpret_cast<ushort4*>(&As[r][c]) = o;
    }
    const ushort_t* ws = &W[(size_t)(bn+r)*DM + q*64];
    #pragma unroll
    for (int i=0;i<8;i++)
      *reinterpret_cast<u16x8*>(&Ws[r][q*64+i*8]) = *reinterpret_cast<const u16x8*>(ws + i*8);
  }
  __syncthreads();
  int lane = tid&63, wid = tid>>6;
  int wm = (wid>>1)<<5, wn = (wid&1)<<5;
  int fr = lane&15, fk = (lane>>4)<<3;
  f32x4 acc[2][2] = {};
  #pragma unroll
  for (int k0=0;k0<DM;k0+=32){
    s16x8 a0 = *reinterpret_cast<const s16x8*>(&As[wm+fr][k0+fk]);
    s16x8 a1 = *reinterpret_cast<const s16x8*>(&As[wm+16+fr][k0+fk]);
    s16x8 b0 = *reinterpret_cast<const s16x8*>(&Ws[wn+fr][k0+fk]);
    s16x8 b1 = *reinterpret_cast<const s16x8*>(&Ws[wn+16+fr][k0+fk]);
    acc[0][0] = __builtin_amdgcn_mfma_f32_16x16x32_bf16(a0,b0,acc[0][0],0,0,0);
    acc[0][1] = __builtin_amdgcn_mfma_f32_16x16x32_bf16(a0,b1,acc[0][1],0,0,0);
    acc[1][0] = __builtin_amdgcn_mfma_f32_16x16x32_bf16(a1,b0,acc[1][0],0,0,0);
    acc[1][1] = __builtin_amdgcn_mfma_f32_16x16x32_bf16(a1,b1,acc[1][1],0,0,0);
  }
  int cr = (lane>>4)<<2, cc = lane&15;
  #pragma unroll
  for (int i=0;i<2;i++)
    #pragma unroll
    for (int j=0;j<2;j++){
      int row = bm + wm + (i<<4) + cr;
      int col = bn + wn + (j<<4) + cc;
      #pragma unroll
      for (int r=0;r<4;r++)
        xzb[(size_t)(row+r)*(2*DI_) + col] = f2bf(acc[i][j][r]);
    }
}

// ---------------- fused conv+SiLU + x_proj (4 rows/block) ----------------
__global__ __launch_bounds__(256) void k_xpc(const ushort_t* __restrict__ xzb,
    const float* __restrict__ cw, const float* __restrict__ cb,
    const float* __restrict__ xw, ushort_t* __restrict__ xcb,
    float* __restrict__ xdbl){
  __shared__ float sxz[7][DI_];
  __shared__ float sx[4][DI_+16];    // stagger-padded: kidx(d)
  int tid = threadIdx.x;
  int m0 = blockIdx.x*4;
  #pragma unroll
  for (int q=0;q<2;q++){
    int idx = q*256 + tid;
    if (idx < 448){
      int i = idx>>6, c8 = (idx&63)<<3;
      int mr = m0 - 3 + i;
      if (mr >= 0){
        u16x8 v = *reinterpret_cast<const u16x8*>(&xzb[(size_t)mr*(2*DI_) + c8]);
        #pragma unroll
        for (int e=0;e<8;e++) sxz[i][c8+e] = bf2f((ushort_t)v[e]);
      } else {
        #pragma unroll
        for (int e=0;e<8;e++) sxz[i][c8+e] = 0.f;
      }
    }
  }
  __syncthreads();
  {
    int r = tid>>6, c8 = (tid&63)<<3;
    int t = (m0 + r) & (L_-1);
    u16x8 outv;
    #pragma unroll
    for (int e=0;e<8;e++){
      int d = c8 + e;
      float acc = cb[d];
      #pragma unroll
      for (int k=0;k<4;k++)
        if (t-3+k >= 0) acc = fmaf(cw[d*4+k], sxz[r+k][d], acc);
      float sv = acc * sigmoidf_(acc);
      sx[r][kidx(d)] = sv;
      outv[e] = (short)f2bf(sv);
    }
    *reinterpret_cast<u16x8*>(&xcb[(size_t)(m0+r)*DI_ + c8]) = outv;
  }
  __syncthreads();
  if (tid < 192){
    int o = tid>>2, q = tid&3;
    const float* wp = &xw[(size_t)o*DI_ + q*128];
    const int qb = q*132;
    float a0=0.f,a1=0.f,a2=0.f,a3=0.f;
    #pragma unroll 8
    for (int k4=0;k4<32;k4++){
      float4 wv = *reinterpret_cast<const float4*>(wp + k4*4);
      int kk = qb + k4*4;
      float4 x0 = *reinterpret_cast<const float4*>(&sx[0][kk]);
      float4 x1 = *reinterpret_cast<const float4*>(&sx[1][kk]);
      float4 x2 = *reinterpret_cast<const float4*>(&sx[2][kk]);
      float4 x3 = *reinterpret_cast<const float4*>(&sx[3][kk]);
      a0 = fmaf(x0.x,wv.x,a0); a0 = fmaf(x0.y,wv.y,a0); a0 = fmaf(x0.z,wv.z,a0); a0 = fmaf(x0.w,wv.w,a0);
      a1 = fmaf(x1.x,wv.x,a1); a1 = fmaf(x1.y,wv.y,a1); a1 = fmaf(x1.z,wv.z,a1); a1 = fmaf(x1.w,wv.w,a1);
      a2 = fmaf(x2.x,wv.x,a2); a2 = fmaf(x2.y,wv.y,a2); a2 = fmaf(x2.z,wv.z,a2); a2 = fmaf(x2.w,wv.w,a2);
      a3 = fmaf(x3.x,wv.x,a3); a3 = fmaf(x3.y,wv.y,a3); a3 = fmaf(x3.z,wv.z,a3); a3 = fmaf(x3.w,wv.w,a3);
    }
    a0 += __shfl_xor(a0,1); a0 += __shfl_xor(a0,2);
    a1 += __shfl_xor(a1,1); a1 += __shfl_xor(a1,2);
    a2 += __shfl_xor(a2,1); a2 += __shfl_xor(a2,2);
    a3 += __shfl_xor(a3,1); a3 += __shfl_xor(a3,2);
    if (q==0){
      xdbl[(size_t)(m0+0)*48+o]=a0;
      xdbl[(size_t)(m0+1)*48+o]=a1;
      xdbl[(size_t)(m0+2)*48+o]=a2;
      xdbl[(size_t)(m0+3)*48+o]=a3;
    }
  }
}

// ================= FUSED SCAN: local summary + decoupled lookback + replay =================
// Flat grid of NCH*64 blocks; vid from ticket => deadlock-free lookback.
__global__ __launch_bounds__(256) void k_scanF(const ushort_t* __restrict__ xcb,
    const float* __restrict__ xdbl, const ushort_t* __restrict__ xzb,
    const float* __restrict__ dtw, const float* __restrict__ dtb,
    const float* __restrict__ A_log, const float* __restrict__ Dp,
    float4* __restrict__ smry, int* __restrict__ ticket,
    int* __restrict__ flags, int lv, ushort_t* __restrict__ y2b){
  __shared__ float sbd[LC][48];      // [t][0:16]=dt, [16:32]=B, [32:48]=C
  __shared__ float sdtw[16][16];
  __shared__ float sxv[LC][16];
  __shared__ float sdel[LC][16];
  __shared__ float szv[LC][16];
  __shared__ float sy[LC][16];
  __shared__ int svid;
  int tid = threadIdx.x;
  if (tid == 0) svid = atomicAdd(ticket, 1);
  __syncthreads();
  int vid = svid;
  int j = vid >> 6, gb = vid & 63, g = gb >> 1, b = gb & 1;
  int n = tid & 15, dg = tid >> 4;
  int d0 = g*16;
  int mbase = b*L_ + j*LC;
  int chain = (b*DI_ + d0)*DS_ + tid;
  // ---- stage chunk data
  {
    const float4* xsrc = reinterpret_cast<const float4*>(xdbl + (size_t)mbase*48);
    reinterpret_cast<float4*>(&sbd[0][0])[tid] = xsrc[tid];
    if (tid < 128) reinterpret_cast<float4*>(&sbd[0][0])[256+tid] = xsrc[256+tid];
    if (tid < 64){
      int row = tid>>1, half = tid&1;
      u16x8 v = *reinterpret_cast<const u16x8*>(&xcb[(size_t)(mbase+row)*DI_ + d0 + half*8]);
      #pragma unroll
      for (int e=0;e<8;e++) sxv[row][half*8+e] = bf2f((ushort_t)v[e]);
    } else if (tid < 128){
      int s = tid-64, row = s>>1, half = s&1;
      u16x8 v = *reinterpret_cast<const u16x8*>(&xzb[(size_t)(mbase+row)*(2*DI_) + DI_ + d0 + half*8]);
      #pragma unroll
      for (int e=0;e<8;e++) szv[row][half*8+e] = bf2f((ushort_t)v[e]);
    } else if (tid < 192){
      int s = tid-128, row = s>>2, c4 = (s&3)<<2;
      *reinterpret_cast<float4*>(&sdtw[row][c4]) =
        *reinterpret_cast<const float4*>(&dtw[(size_t)(d0+row)*16 + c4]);
    }
  }
  __syncthreads();
  // ---- delta = softplus(dt @ dtw^T + dtb)
  #pragma unroll
  for (int q=0;q<2;q++){
    int p = q*256 + tid;
    int t = p>>4, dd = p&15;
    float acc = dtb[d0+dd];
    #pragma unroll
    for (int k=0;k<16;k++) acc = fmaf(sbd[t][k], sdtw[dd][k], acc);
    sdel[t][dd] = (acc>20.f)? acc : log1pf(__expf(acc));
  }
  __syncthreads();
  float a = -__expf(A_log[(d0+dg)*DS_ + n]);
  // ---- pass 1: local summary (zero init)
  {
    float hs=0.f, hh=0.f, cp=1.f;
    #pragma unroll
    for (int tt=0; tt<LC; tt+=8){
      float dA8[8], dBu8[8];
      #pragma unroll
      for (int t=0;t<8;t++){
        float dv = sdel[tt+t][dg];
        dA8[t]  = __expf(dv*a);
        dBu8[t] = dv * sxv[tt+t][dg] * sbd[tt+t][16+n];
      }
      #pragma unroll
      for (int t=0;t<8;t++){
        float mix = fmaf(ALPHA_, hs-hh, hh);
        hs = fmaf(dA8[t], hs, dBu8[t]);
        hh = fmaf(dA8[t], mix, dBu8[t]);
        cp *= dA8[t];
      }
    }
    smry[(size_t)j*NCHAIN + chain] = float4{cp, hs, hh, 0.f};
  }
  // publish: every thread fences its own store, then one flag set
  __threadfence();
  __syncthreads();
  if (tid == 0) atomicExch(&flags[vid], lv);
  // ---- lookback over predecessor aggregates
  float s0 = 0.f, h0 = 0.f;
  if (j > 0){
    for (int jj = tid; jj < j; jj += 256){
      while (atomicAdd(&flags[(jj<<6) + gb], 0) < lv)
        __builtin_amdgcn_s_sleep(4);
    }
    __syncthreads();
    __threadfence();
    #pragma unroll 4
    for (int jj=0; jj<j; ++jj){
      float4 v = smry[(size_t)jj*NCHAIN + chain];
      float snew = fmaf(v.x, s0, v.y);
      h0 = fmaf(v.x, fmaf(BETA_LC, h0-s0, s0), v.z);
      s0 = snew;
    }
  }
  // ---- pass 2: replay with true init, y reduction, gate, store
  float hs = s0, hh = h0;
  #pragma unroll
  for (int tt=0; tt<LC; tt+=8){
    float dA8[8], dBu8[8], yv8[8];
    #pragma unroll
    for (int t=0;t<8;t++){
      float dv = sdel[tt+t][dg];
      dA8[t]  = __expf(dv*a);
      dBu8[t] = dv * sxv[tt+t][dg] * sbd[tt+t][16+n];
    }
    #pragma unroll
    for (int t=0;t<8;t++){
      float mix = fmaf(ALPHA_, hs-hh, hh);
      hs = fmaf(dA8[t], hs, dBu8[t]);
      hh = fmaf(dA8[t], mix, dBu8[t]);
      yv8[t] = hh * sbd[tt+t][32+n];
    }
    #pragma unroll
    for (int t=0;t<8;t++){
      yv8[t] += __shfl_xor(yv8[t],1,16);
      yv8[t] += __shfl_xor(yv8[t],2,16);
      yv8[t] += __shfl_xor(yv8[t],4,16);
      yv8[t] += __shfl_xor(yv8[t],8,16);
    }
    if (n==0){
      #pragma unroll
      for (int t=0;t<8;t++) sy[tt+t][dg] = yv8[t];
    }
  }
  __syncthreads();
  float dpv = Dp[d0 + (tid&15)];
  #pragma unroll
  for (int idx=0; idx<2; ++idx){
    int flat = idx*256 + tid;
    int t2 = flat>>4, dd = flat&15;
    float xvv = sxv[t2][dd];
    float zv  = szv[t2][dd];
    float yfin = (sy[t2][dd] + dpv*xvv) * (zv*sigmoidf_(zv));
    y2b[(size_t)(mbase + t2)*DI_ + d0 + dd] = f2bf(yfin);
  }
}

// ---------------- out_proj GEMM (bf16 MFMA) + residual, h += y2 @ W^T ----------------
__global__ __launch_bounds__(256) void k_gemm_out(const ushort_t* __restrict__ A,
    const ushort_t* __restrict__ W, float* __restrict__ h){
  __shared__ ushort_t As[32][264];
  __shared__ ushort_t Ws[64][264];
  int bm = blockIdx.y<<5, bn = blockIdx.x<<6;
  int tid = threadIdx.x;
  int lane = tid&63, wid = tid>>6;
  int wm = (wid>>1)<<4, wn = (wid&1)<<5;
  int fr = lane&15, fk = (lane>>4)<<3;
  f32x4 acc[2] = {};
  for (int k0=0;k0<DI_;k0+=256){
    {
      int r = tid>>3, q = tid&7;
      const ushort_t* src = &A[(size_t)(bm+r)*DI_ + k0 + q*32];
      #pragma unroll
      for (int i=0;i<4;i++)
        *reinterpret_cast<u16x8*>(&As[r][q*32+i*8]) = *reinterpret_cast<const u16x8*>(src+i*8);
      int r2 = tid>>2, q2 = tid&3;
      const ushort_t* ws = &W[(size_t)(bn+r2)*DI_ + k0 + q2*64];
      #pragma unroll
      for (int i=0;i<8;i++)
        *reinterpret_cast<u16x8*>(&Ws[r2][q2*64+i*8]) = *reinterpret_cast<const u16x8*>(ws+i*8);
    }
    __syncthreads();
    #pragma unroll
    for (int k=0;k<256;k+=32){
      s16x8 a0 = *reinterpret_cast<const s16x8*>(&As[wm+fr][k+fk]);
      s16x8 b0 = *reinterpret_cast<const s16x8*>(&Ws[wn+fr][k+fk]);
      s16x8 b1 = *reinterpret_cast<const s16x8*>(&Ws[wn+16+fr][k+fk]);
      acc[0] = __builtin_amdgcn_mfma_f32_16x16x32_bf16(a0,b0,acc[0],0,0,0);
      acc[1] = __builtin_amdgcn_mfma_f32_16x16x32_bf16(a0,b1,acc[1],0,0,0);
    }
    __syncthreads();
  }
  int cr = (lane>>4)<<2, cc = lane&15;
  #pragma unroll
  for (int jj=0;jj<2;jj++){
    int row = bm + wm + cr;
    int col = bn + wn + (jj<<4) + cc;
    #pragma unroll
    for (int r=0;r<4;r++){
      size_t idx2 = (size_t)(row+r)*DM + col;
      h[idx2] += acc[jj][r];
    }
  }
}

// ---------------- masked pooling ----------------
__global__ __launch_bounds__(256) void k_pool(const float* __restrict__ h,
    const int* __restrict__ mask, float* __restrict__ partial){
  int p = blockIdx.x, b = blockIdx.y, d = threadIdx.x;
  int t0 = p*64;
  __shared__ float sm[64];
  if (d < 64) sm[d] = (float)mask[b*L_ + t0 + d];
  __syncthreads();
  const float* hp = &h[(size_t)(b*L_ + t0)*DM + d];
  float s = 0.f;
  #pragma unroll 8
  for (int i=0;i<64;i++)
    s = fmaf(sm[i], hp[(size_t)i*DM], s);
  partial[(size_t)(b*16+p)*DM + d] = s;
}

// ---------------- final: count + LN + classifier ----------------
__global__ __launch_bounds__(256) void k_head(const float* __restrict__ partial,
    const int* __restrict__ mask, const float* __restrict__ nw, const float* __restrict__ nb,
    const float* __restrict__ cw, const float* __restrict__ cb, float* __restrict__ out){
  int b = blockIdx.x, d = threadIdx.x;
  int4 mi = *reinterpret_cast<const int4*>(&mask[b*L_ + d*4]);
  float cnt = (float)(mi.x + mi.y + mi.z + mi.w);
  #pragma unroll
  for (int o=32;o>0;o>>=1) cnt += __shfl_down(cnt,o);
  __shared__ float ac[4];
  __shared__ float scnt;
  int wid = d>>6, lane = d&63;
  if (lane==0) ac[wid] = cnt;
  __syncthreads();
  if (d==0) scnt = ac[0]+ac[1]+ac[2]+ac[3];
  __syncthreads();
  float s = 0.f;
  #pragma unroll
  for (int p=0;p<16;p++) s += partial[(size_t)(b*16+p)*DM + d];
  float v = s / scnt;
  float s1 = v, s2 = v*v;
  #pragma unroll
  for (int o=32;o>0;o>>=1){ s1 += __shfl_down(s1,o); s2 += __shfl_down(s2,o); }
  __shared__ float a1[4], a2[4];
  __shared__ float mv[2];
  if (lane==0){ a1[wid]=s1; a2[wid]=s2; }
  __syncthreads();
  if (d==0){
    float t1=a1[0]+a1[1]+a1[2]+a1[3];
    float t2=a2[0]+a2[1]+a2[2]+a2[3];
    float m = t1/(float)DM;
    mv[0]=m; mv[1]=rsqrtf(t2/(float)DM - m*m + 1e-5f);
  }
  __syncthreads();
  __shared__ float sp[DM];
  sp[d] = (v-mv[0])*mv[1]*nw[d]+nb[d];
  __syncthreads();
  __shared__ float cpart[NC_][16];
  if (d < NC_*16){
    int c = d>>4, q = d&15;
    float acc = 0.f;
    #pragma unroll
    for (int k=0;k<16;k++) acc = fmaf(sp[q*16+k], cw[(size_t)c*DM+q*16+k], acc);
    cpart[c][q] = acc;
  }
  __syncthreads();
  if (d < NC_){
    float acc = cb[d];
    #pragma unroll
    for (int q=0;q<16;q++) acc += cpart[d][q];
    out[b*NC_+d] = acc;
  }
}

extern "C" void kernel_launch(void* const* d_in, const int* in_sizes, int n_in,
                              void* d_out, int out_size, void* d_ws, size_t ws_size,
                              hipStream_t stream){
  const float* emb   = (const float*)d_in[0];
  const float* pos   = (const float*)d_in[1];
  const float* ln_w  = (const float*)d_in[2];
  const float* ln_b  = (const float*)d_in[3];
  const float* ipw   = (const float*)d_in[4];
  const float* cw    = (const float*)d_in[5];
  const float* cb    = (const float*)d_in[6];
  const float* xpw   = (const float*)d_in[7];
  const float* dtw   = (const float*)d_in[8];
  const float* dtb   = (const float*)d_in[9];
  const float* A_log = (const float*)d_in[10];
  const float* Dp    = (const float*)d_in[11];
  const float* opw   = (const float*)d_in[12];
  const float* nw    = (const float*)d_in[13];
  const float* nb    = (const float*)d_in[14];
  const float* clw   = (const float*)d_in[15];
  const float* clb   = (const float*)d_in[16];
  const int*   ids   = (const int*)d_in[17];
  const int*   mask  = (const int*)d_in[18];
  float* out = (float*)d_out;

  float* ws    = (float*)d_ws;
  float* h     = ws;                     // 524288 floats
  float* xdbl  = h + 524288;             // 98304
  float* part  = xdbl + 98304;           // 8192
  float4* smry = (float4*)(part + 8192); // 524288 float4
  int* syncreg = (int*)((float*)smry + 2097152); // 8 tickets + 2048 flags (+pad to 2064)
  int* tickets = syncreg;
  int* flags   = syncreg + 8;
  ushort_t* xzb  = (ushort_t*)(syncreg + 2064); // 2048*1024
  ushort_t* xcb  = xzb + 2097152;        // 2048*512
  ushort_t* y2b  = xcb + 1048576;        // 2048*512
  ushort_t* ipwb = y2b + 1048576;        // 6*1024*256
  ushort_t* opwb = ipwb + 1572864;       // 6*256*512

  hipMemsetAsync(syncreg, 0, 2064*sizeof(int), stream);
  const int NA = 6*2*DI_*DM, NB = 6*DM*DI_;
  k_cvt2<<<dim3((NA+NB)/1024), 256, 0, stream>>>(ipw, NA, opw, ipwb, opwb, NA+NB);
  k_embed<<<dim3(B_*L_), dim3(DM), 0, stream>>>(emb, pos, ids, h);

  for (int l=0; l<NL_; ++l){
    k_gemm_ln<<<dim3(16, 32), 256, 0, stream>>>(
        h, ipwb + (size_t)l*2*DI_*DM, ln_w + l*DM, ln_b + l*DM, xzb);
    k_xpc<<<dim3((B_*L_)/4), 256, 0, stream>>>(
        xzb, cw + l*DI_*DC_, cb + l*DI_, xpw + (size_t)l*48*DI_, xcb, xdbl);
    k_scanF<<<dim3(NCH*64), 256, 0, stream>>>(
        xcb, xdbl, xzb, dtw + (size_t)l*DI_*16, dtb + l*DI_,
        A_log + (size_t)l*DI_*DS_, Dp + l*DI_, smry,
        &tickets[l], flags, l+1, y2b);
    k_gemm_out<<<dim3(DM/64, (B_*L_)/32), 256, 0, stream>>>(
        y2b, opwb + (size_t)l*DM*DI_, h);
  }
  k_pool<<<dim3(16, B_), 256, 0, stream>>>(h, mask, part);
  k_head<<<dim3(B_), 256, 0, stream>>>(part, mask, nw, nb, clw, clb, out);
}

// Round 11
// 1870.910 us; speedup vs baseline: 1.3403x; 1.3403x over previous
//
#include <hip/hip_runtime.h>
#include <hip/hip_cooperative_groups.h>
#include <math.h>

namespace cg = cooperative_groups;

#define B_ 2
#define L_ 1024
#define DM 256
#define NL_ 6
#define DI_ 512
#define DS_ 16
#define NC_ 10
#define ALPHA_ 0.1f
#define LC 32
#define NCH 32
#define NCHAIN 16384
#define BETA_LC 0.034336838202925124f  // 0.9^32

typedef unsigned short ushort_t;
typedef __attribute__((ext_vector_type(8))) short s16x8;
typedef __attribute__((ext_vector_type(4))) float f32x4;
typedef __attribute__((ext_vector_type(8))) unsigned short u16x8;

__device__ __forceinline__ float sigmoidf_(float x){ return 1.f/(1.f+__expf(-x)); }
__device__ __forceinline__ ushort_t f2bf(float f){
  union{float f;unsigned u;} c; c.f=f; unsigned u=c.u;
  return (ushort_t)((u + 0x7fffu + ((u>>16)&1u))>>16);
}
__device__ __forceinline__ float bf2f(ushort_t h){
  union{unsigned u;float f;} c; c.u = ((unsigned)h)<<16; return c.f;
}
__device__ __forceinline__ int kidx(int d){ return d + ((d>>7)<<2); }

// ===================== COOPERATIVE single-kernel path =====================
__global__ __launch_bounds__(256, 2) void k_net(
    const float* __restrict__ emb, const float* __restrict__ pos,
    const int* __restrict__ ids, const int* __restrict__ maskp,
    const float* __restrict__ ln_w, const float* __restrict__ ln_b,
    const float* __restrict__ ipw, const float* __restrict__ opw,
    const float* __restrict__ cw_a, const float* __restrict__ cb_a,
    const float* __restrict__ xw_a, const float* __restrict__ dtw_a,
    const float* __restrict__ dtb_a, const float* __restrict__ al_a,
    const float* __restrict__ dp_a,
    const float* __restrict__ nw, const float* __restrict__ nb,
    const float* __restrict__ clw, const float* __restrict__ clb,
    float* __restrict__ outp,
    float* __restrict__ hbuf, float* __restrict__ xdbl, float* __restrict__ part,
    float4* __restrict__ smry, float2* __restrict__ initA,
    ushort_t* __restrict__ xzb, ushort_t* __restrict__ xcb,
    ushort_t* __restrict__ y2b, ushort_t* __restrict__ ipwb,
    ushort_t* __restrict__ opwb)
{
  cg::grid_group grid = cg::this_grid();
  __shared__ __align__(16) char smem[26368];
  const int bid = blockIdx.x, tid = threadIdx.x;
  const int GS = gridDim.x;
  const int lane = tid & 63, wv = tid >> 6;
  const int fr = lane & 15, fk = (lane>>4)<<3;
  const int cr = (lane>>4)<<2, cc = lane & 15;
  const int wm16 = (wv>>1)<<4, wn32 = (wv&1)<<5;

  // ---- P0: weight cvt + embed ----
  {
    const int NA = NL_*2*DI_*DM, NBn = NL_*DM*DI_;
    const int NT4 = (NA+NBn)>>2;
    for (int i4 = bid*256 + tid; i4 < NT4; i4 += GS*256){
      int i = i4<<2;
      const float* s; ushort_t* dst; int k = i;
      if (i < NA){ s = ipw; dst = ipwb; } else { s = opw; dst = opwb; k = i-NA; }
      float4 v = *reinterpret_cast<const float4*>(&s[k]);
      ushort4 r; r.x=f2bf(v.x); r.y=f2bf(v.y); r.z=f2bf(v.z); r.w=f2bf(v.w);
      *reinterpret_cast<ushort4*>(&dst[k]) = r;
    }
    for (int row = bid; row < B_*L_; row += GS)
      hbuf[(size_t)row*DM + tid] =
        emb[(size_t)ids[row]*DM + tid] + pos[(size_t)(row & (L_-1))*DM + tid];
  }
  grid.sync();

  for (int l=0; l<NL_; ++l){
    const ushort_t* Wip = ipwb + (size_t)l*2*DI_*DM;
    const ushort_t* Wop = opwb + (size_t)l*DM*DI_;
    const float* lw = ln_w + l*DM;  const float* lb = ln_b + l*DM;
    const float* cw = cw_a + l*DI_*4; const float* cb = cb_a + l*DI_;
    const float* xw = xw_a + (size_t)l*48*DI_;
    const float* dtw = dtw_a + (size_t)l*DI_*16;
    const float* dtb = dtb_a + l*DI_;
    const float* alog = al_a + (size_t)l*DI_*DS_;
    const float* Dp = dp_a + l*DI_;

    // ---- P1: LN + in_proj GEMM (1024 tiles of 32x64) -> xzb ----
    for (int tile = bid; tile < 1024; tile += GS){
      int bmt = tile >> 4, bnt = tile & 15;
      float* smean = (float*)smem;
      float* srstd = smean + 32;
      ushort_t* As = (ushort_t*)(smem + 256);     // [32][72]
      ushort_t* Ws = As + 32*72;                  // [64][72]
      {
        int r = tid>>3, s = tid&7;
        const float* src = &hbuf[(size_t)(bmt*32+r)*DM + s*32];
        float s1=0.f, s2=0.f;
        #pragma unroll
        for (int i=0;i<8;i++){
          float4 v = *reinterpret_cast<const float4*>(src + i*4);
          s1 += v.x+v.y+v.z+v.w;
          s2 += v.x*v.x+v.y*v.y+v.z*v.z+v.w*v.w;
        }
        s1 += __shfl_xor(s1,1); s2 += __shfl_xor(s2,1);
        s1 += __shfl_xor(s1,2); s2 += __shfl_xor(s2,2);
        s1 += __shfl_xor(s1,4); s2 += __shfl_xor(s2,4);
        if (s==0){
          float mean = s1*(1.f/DM);
          smean[r] = mean;
          srstd[r] = rsqrtf(s2*(1.f/DM) - mean*mean + 1e-5f);
        }
      }
      __syncthreads();
      f32x4 acc0 = {}, acc1 = {};
      for (int kk=0; kk<4; ++kk){
        {
          int r = tid>>3, c8 = (tid&7)<<3;
          float mean = smean[r], rs = srstd[r];
          const float* src = &hbuf[(size_t)(bmt*32+r)*DM + kk*64 + c8];
          float4 v0 = *reinterpret_cast<const float4*>(src);
          float4 v1 = *reinterpret_cast<const float4*>(src+4);
          const float* lwp = &lw[kk*64+c8];
          const float* lbp = &lb[kk*64+c8];
          u16x8 ov;
          ov[0]=(short)f2bf((v0.x-mean)*rs*lwp[0]+lbp[0]);
          ov[1]=(short)f2bf((v0.y-mean)*rs*lwp[1]+lbp[1]);
          ov[2]=(short)f2bf((v0.z-mean)*rs*lwp[2]+lbp[2]);
          ov[3]=(short)f2bf((v0.w-mean)*rs*lwp[3]+lbp[3]);
          ov[4]=(short)f2bf((v1.x-mean)*rs*lwp[4]+lbp[4]);
          ov[5]=(short)f2bf((v1.y-mean)*rs*lwp[5]+lbp[5]);
          ov[6]=(short)f2bf((v1.z-mean)*rs*lwp[6]+lbp[6]);
          ov[7]=(short)f2bf((v1.w-mean)*rs*lwp[7]+lbp[7]);
          *reinterpret_cast<u16x8*>(&As[r*72 + c8]) = ov;
          int r2 = tid>>2, c16 = (tid&3)<<4;
          const ushort_t* wsrc = &Wip[(size_t)(bnt*64+r2)*DM + kk*64 + c16];
          *reinterpret_cast<u16x8*>(&Ws[r2*72+c16])   = *reinterpret_cast<const u16x8*>(wsrc);
          *reinterpret_cast<u16x8*>(&Ws[r2*72+c16+8]) = *reinterpret_cast<const u16x8*>(wsrc+8);
        }
        __syncthreads();
        #pragma unroll
        for (int ks=0; ks<64; ks+=32){
          s16x8 a0 = *reinterpret_cast<const s16x8*>(&As[(wm16+fr)*72 + ks+fk]);
          s16x8 b0 = *reinterpret_cast<const s16x8*>(&Ws[(wn32+fr)*72 + ks+fk]);
          s16x8 b1 = *reinterpret_cast<const s16x8*>(&Ws[(wn32+16+fr)*72 + ks+fk]);
          acc0 = __builtin_amdgcn_mfma_f32_16x16x32_bf16(a0,b0,acc0,0,0,0);
          acc1 = __builtin_amdgcn_mfma_f32_16x16x32_bf16(a0,b1,acc1,0,0,0);
        }
        __syncthreads();
      }
      #pragma unroll
      for (int r=0;r<4;r++){
        int row = bmt*32 + wm16 + cr + r;
        xzb[(size_t)row*(2*DI_) + bnt*64 + wn32 + cc]      = f2bf(acc0[r]);
        xzb[(size_t)row*(2*DI_) + bnt*64 + wn32 + 16 + cc] = f2bf(acc1[r]);
      }
    }
    grid.sync();

    // ---- P2: conv+SiLU + x_proj (2 rows/vblock) -> xcb, xdbl ----
    for (int vb = bid; vb < 1024; vb += GS){
      float* sxz = (float*)smem;          // [5][512]
      float* sx  = sxz + 2560;            // [2][528]
      int m0 = vb*2;
      for (int t4 = tid; t4 < 320; t4 += 256){
        int i = t4 >> 6, c8 = (t4 & 63) << 3;
        int mr = m0 - 3 + i;
        if (mr >= 0){
          u16x8 v = *reinterpret_cast<const u16x8*>(&xzb[(size_t)mr*(2*DI_) + c8]);
          #pragma unroll
          for (int e=0;e<8;e++) sxz[i*512 + c8 + e] = bf2f((ushort_t)v[e]);
        } else {
          #pragma unroll
          for (int e=0;e<8;e++) sxz[i*512 + c8 + e] = 0.f;
        }
      }
      __syncthreads();
      {
        int r = tid >> 7, d4 = (tid & 127) << 2;
        int m = m0 + r, t = m & (L_-1);
        ushort4 ov;
        #pragma unroll
        for (int e=0;e<4;e++){
          int d = d4+e;
          float acc = cb[d];
          #pragma unroll
          for (int k=0;k<4;k++)
            if (t-3+k >= 0) acc = fmaf(cw[d*4+k], sxz[(r+k)*512 + d], acc);
          float sv = acc * sigmoidf_(acc);
          sx[r*528 + kidx(d)] = sv;
          ((ushort_t*)&ov)[e] = f2bf(sv);
        }
        *reinterpret_cast<ushort4*>(&xcb[(size_t)m*DI_ + d4]) = ov;
      }
      __syncthreads();
      if (tid < 192){
        int o = tid>>2, q = tid&3;
        const float* wp = &xw[(size_t)o*DI_ + q*128];
        const int qb = q*132;
        float a0=0.f, a1=0.f;
        #pragma unroll 8
        for (int k4=0;k4<32;k4++){
          float4 wvv = *reinterpret_cast<const float4*>(wp + k4*4);
          int kk2 = qb + k4*4;
          float4 x0 = *reinterpret_cast<const float4*>(&sx[kk2]);
          float4 x1 = *reinterpret_cast<const float4*>(&sx[528 + kk2]);
          a0 = fmaf(x0.x,wvv.x,a0); a0 = fmaf(x0.y,wvv.y,a0);
          a0 = fmaf(x0.z,wvv.z,a0); a0 = fmaf(x0.w,wvv.w,a0);
          a1 = fmaf(x1.x,wvv.x,a1); a1 = fmaf(x1.y,wvv.y,a1);
          a1 = fmaf(x1.z,wvv.z,a1); a1 = fmaf(x1.w,wvv.w,a1);
        }
        a0 += __shfl_xor(a0,1); a0 += __shfl_xor(a0,2);
        a1 += __shfl_xor(a1,1); a1 += __shfl_xor(a1,2);
        if (q==0){
          xdbl[(size_t)m0*48 + o]     = a0;
          xdbl[(size_t)(m0+1)*48 + o] = a1;
        }
      }
      __syncthreads();
    }
    grid.sync();

    // ---- P3: scanA (2048 vblocks) -> smry ----
    for (int vb = bid; vb < 2048; vb += GS){
      int j = vb >> 6, gb = vb & 63, g = gb >> 1, bb = gb & 1;
      int d0 = g*16, mbase = bb*L_ + j*LC;
      float* sbd  = (float*)smem;       // [32][48]
      float* sdtw = sbd + 1536;         // [16][16]
      float* sxv  = sdtw + 256;         // [32][16]
      float* sdel = sxv + 512;          // [32][16]
      {
        const float4* xsrc = reinterpret_cast<const float4*>(xdbl + (size_t)mbase*48);
        reinterpret_cast<float4*>(sbd)[tid] = xsrc[tid];
        if (tid < 128) reinterpret_cast<float4*>(sbd)[256+tid] = xsrc[256+tid];
        if (tid < 64){
          int row = tid>>1, half = tid&1;
          u16x8 v = *reinterpret_cast<const u16x8*>(&xcb[(size_t)(mbase+row)*DI_ + d0 + half*8]);
          #pragma unroll
          for (int e=0;e<8;e++) sxv[row*16 + half*8 + e] = bf2f((ushort_t)v[e]);
        } else if (tid < 128){
          int s = tid-64, row = s>>2, c4 = (s&3)<<2;
          *reinterpret_cast<float4*>(&sdtw[row*16+c4]) =
            *reinterpret_cast<const float4*>(&dtw[(size_t)(d0+row)*16 + c4]);
        }
      }
      __syncthreads();
      #pragma unroll
      for (int q=0;q<2;q++){
        int p = q*256 + tid, t = p>>4, dd = p&15;
        float acc = dtb[d0+dd];
        #pragma unroll
        for (int k=0;k<16;k++) acc = fmaf(sbd[t*48+k], sdtw[dd*16+k], acc);
        sdel[t*16+dd] = (acc>20.f)? acc : log1pf(__expf(acc));
      }
      __syncthreads();
      int n = tid&15, dg = tid>>4;
      float a = -__expf(alog[(d0+dg)*DS_ + n]);
      float hs=0.f, hh=0.f, cp=1.f;
      #pragma unroll
      for (int tt=0; tt<LC; tt+=8){
        float dA8[8], dBu8[8];
        #pragma unroll
        for (int t=0;t<8;t++){
          float dv = sdel[(tt+t)*16 + dg];
          dA8[t]  = __expf(dv*a);
          dBu8[t] = dv * sxv[(tt+t)*16 + dg] * sbd[(tt+t)*48 + 16+n];
        }
        #pragma unroll
        for (int t=0;t<8;t++){
          float mix = fmaf(ALPHA_, hs-hh, hh);
          hs = fmaf(dA8[t], hs, dBu8[t]);
          hh = fmaf(dA8[t], mix, dBu8[t]);
          cp *= dA8[t];
        }
      }
      smry[(size_t)j*NCHAIN + (size_t)(bb*DI_+d0)*DS_ + tid] = float4{cp,hs,hh,0.f};
      __syncthreads();
    }
    grid.sync();

    // ---- P3.5: scanB -> initA ----
    for (int c = bid*256 + tid; c < NCHAIN; c += GS*256){
      float hs=0.f, hh=0.f;
      #pragma unroll
      for (int j=0;j<NCH;j++){
        size_t o = (size_t)j*NCHAIN + c;
        float4 v = smry[o];
        initA[o] = float2{hs,hh};
        float snew = fmaf(v.x, hs, v.y);
        hh = fmaf(v.x, fmaf(BETA_LC, hh-hs, hs), v.z);
        hs = snew;
      }
    }
    grid.sync();

    // ---- P4: scanC (2048 vblocks) -> y2b ----
    for (int vb = bid; vb < 2048; vb += GS){
      int j = vb >> 6, gb = vb & 63, g = gb >> 1, bb = gb & 1;
      int d0 = g*16, mbase = bb*L_ + j*LC;
      float2 iv = initA[(size_t)j*NCHAIN + (size_t)(bb*DI_+d0)*DS_ + tid];
      float* sbd  = (float*)smem;       // [32][48]
      float* sdtw = sbd + 1536;
      float* sxv  = sdtw + 256;
      float* sdel = sxv + 512;
      float* szv  = sdel + 512;
      float* sy   = szv + 512;
      {
        const float4* xsrc = reinterpret_cast<const float4*>(xdbl + (size_t)mbase*48);
        reinterpret_cast<float4*>(sbd)[tid] = xsrc[tid];
        if (tid < 128) reinterpret_cast<float4*>(sbd)[256+tid] = xsrc[256+tid];
        if (tid < 64){
          int row = tid>>1, half = tid&1;
          u16x8 v = *reinterpret_cast<const u16x8*>(&xcb[(size_t)(mbase+row)*DI_ + d0 + half*8]);
          #pragma unroll
          for (int e=0;e<8;e++) sxv[row*16 + half*8 + e] = bf2f((ushort_t)v[e]);
        } else if (tid < 128){
          int s = tid-64, row = s>>1, half = s&1;
          u16x8 v = *reinterpret_cast<const u16x8*>(&xzb[(size_t)(mbase+row)*(2*DI_) + DI_ + d0 + half*8]);
          #pragma unroll
          for (int e=0;e<8;e++) szv[row*16 + half*8 + e] = bf2f((ushort_t)v[e]);
        } else if (tid < 192){
          int s = tid-128, row = s>>2, c4 = (s&3)<<2;
          *reinterpret_cast<float4*>(&sdtw[row*16+c4]) =
            *reinterpret_cast<const float4*>(&dtw[(size_t)(d0+row)*16 + c4]);
        }
      }
      __syncthreads();
      #pragma unroll
      for (int q=0;q<2;q++){
        int p = q*256 + tid, t = p>>4, dd = p&15;
        float acc = dtb[d0+dd];
        #pragma unroll
        for (int k=0;k<16;k++) acc = fmaf(sbd[t*48+k], sdtw[dd*16+k], acc);
        sdel[t*16+dd] = (acc>20.f)? acc : log1pf(__expf(acc));
      }
      __syncthreads();
      int n = tid&15, dg = tid>>4;
      float a = -__expf(alog[(d0+dg)*DS_ + n]);
      float hs = iv.x, hh = iv.y;
      #pragma unroll
      for (int tt=0; tt<LC; tt+=8){
        float dA8[8], dBu8[8], yv8[8];
        #pragma unroll
        for (int t=0;t<8;t++){
          float dv = sdel[(tt+t)*16 + dg];
          dA8[t]  = __expf(dv*a);
          dBu8[t] = dv * sxv[(tt+t)*16 + dg] * sbd[(tt+t)*48 + 16+n];
        }
        #pragma unroll
        for (int t=0;t<8;t++){
          float mix = fmaf(ALPHA_, hs-hh, hh);
          hs = fmaf(dA8[t], hs, dBu8[t]);
          hh = fmaf(dA8[t], mix, dBu8[t]);
          yv8[t] = hh * sbd[(tt+t)*48 + 32+n];
        }
        #pragma unroll
        for (int t=0;t<8;t++){
          yv8[t] += __shfl_xor(yv8[t],1,16);
          yv8[t] += __shfl_xor(yv8[t],2,16);
          yv8[t] += __shfl_xor(yv8[t],4,16);
          yv8[t] += __shfl_xor(yv8[t],8,16);
        }
        if (n==0){
          #pragma unroll
          for (int t=0;t<8;t++) sy[(tt+t)*16 + dg] = yv8[t];
        }
      }
      __syncthreads();
      float dpv = Dp[d0 + (tid&15)];
      #pragma unroll
      for (int idx=0; idx<2; ++idx){
        int flat = idx*256 + tid;
        int t2 = flat>>4, dd = flat&15;
        float xvv = sxv[t2*16+dd];
        float zv  = szv[t2*16+dd];
        float yfin = (sy[t2*16+dd] + dpv*xvv) * (zv*sigmoidf_(zv));
        y2b[(size_t)(mbase + t2)*DI_ + d0 + dd] = f2bf(yfin);
      }
      __syncthreads();
    }
    grid.sync();

    // ---- P5: out_proj (1024 vblocks = 256 tiles x 4 K-slices), h += via atomicAdd ----
    for (int vb = bid; vb < 1024; vb += GS){
      int t5 = vb >> 2, kq = vb & 3;
      int bmt = t5 >> 2, bnt = t5 & 3;
      ushort_t* As = (ushort_t*)smem;     // [32][136]
      ushort_t* Ws = As + 32*136;         // [64][136]
      {
        int r = tid>>3, c16 = (tid&7)<<4;
        const ushort_t* src = &y2b[(size_t)(bmt*32+r)*DI_ + kq*128 + c16];
        *reinterpret_cast<u16x8*>(&As[r*136 + c16])   = *reinterpret_cast<const u16x8*>(src);
        *reinterpret_cast<u16x8*>(&As[r*136 + c16+8]) = *reinterpret_cast<const u16x8*>(src+8);
        int r2 = tid>>2, c32 = (tid&3)<<5;
        const ushort_t* wsrc = &Wop[(size_t)(bnt*64+r2)*DI_ + kq*128 + c32];
        #pragma unroll
        for (int i=0;i<4;i++)
          *reinterpret_cast<u16x8*>(&Ws[r2*136 + c32 + i*8]) =
            *reinterpret_cast<const u16x8*>(wsrc + i*8);
      }
      __syncthreads();
      f32x4 acc0={}, acc1={};
      #pragma unroll
      for (int ks=0; ks<128; ks+=32){
        s16x8 a0 = *reinterpret_cast<const s16x8*>(&As[(wm16+fr)*136 + ks+fk]);
        s16x8 b0 = *reinterpret_cast<const s16x8*>(&Ws[(wn32+fr)*136 + ks+fk]);
        s16x8 b1 = *reinterpret_cast<const s16x8*>(&Ws[(wn32+16+fr)*136 + ks+fk]);
        acc0 = __builtin_amdgcn_mfma_f32_16x16x32_bf16(a0,b0,acc0,0,0,0);
        acc1 = __builtin_amdgcn_mfma_f32_16x16x32_bf16(a0,b1,acc1,0,0,0);
      }
      #pragma unroll
      for (int r=0;r<4;r++){
        int row = bmt*32 + wm16 + cr + r;
        atomicAdd(&hbuf[(size_t)row*DM + bnt*64 + wn32 + cc], acc0[r]);
        atomicAdd(&hbuf[(size_t)row*DM + bnt*64 + wn32 + 16 + cc], acc1[r]);
      }
      __syncthreads();
    }
    grid.sync();
  }

  // ---- pool ----
  for (int pb = bid; pb < 32; pb += GS){
    int p = pb >> 1, bb = pb & 1;
    float* sm = (float*)smem;
    if (tid < 64) sm[tid] = (float)maskp[bb*L_ + p*64 + tid];
    __syncthreads();
    const float* hp = &hbuf[(size_t)(bb*L_ + p*64)*DM + tid];
    float s = 0.f;
    #pragma unroll 8
    for (int i=0;i<64;i++) s = fmaf(sm[i], hp[(size_t)i*DM], s);
    part[(size_t)(bb*16+p)*DM + tid] = s;
    __syncthreads();
  }
  grid.sync();

  // ---- head ----
  for (int hb = bid; hb < 2; hb += GS){
    int b = hb, d = tid;
    float* sp    = (float*)smem;   // 256
    float* cpart = sp + 256;       // 160
    float* aux   = cpart + 160;    // 16
    int4 mi = *reinterpret_cast<const int4*>(&maskp[b*L_ + d*4]);
    float cnt = (float)(mi.x + mi.y + mi.z + mi.w);
    #pragma unroll
    for (int o=32;o>0;o>>=1) cnt += __shfl_down(cnt,o);
    int wd = d>>6, ln2 = d&63;
    if (ln2==0) aux[wd] = cnt;
    __syncthreads();
    if (d==0) aux[14] = aux[0]+aux[1]+aux[2]+aux[3];
    __syncthreads();
    float s = 0.f;
    #pragma unroll
    for (int p=0;p<16;p++) s += part[(size_t)(b*16+p)*DM + d];
    float v = s / aux[14];
    float s1 = v, s2 = v*v;
    #pragma unroll
    for (int o=32;o>0;o>>=1){ s1 += __shfl_down(s1,o); s2 += __shfl_down(s2,o); }
    if (ln2==0){ aux[4+wd]=s1; aux[8+wd]=s2; }
    __syncthreads();
    if (d==0){
      float t1=aux[4]+aux[5]+aux[6]+aux[7];
      float t2=aux[8]+aux[9]+aux[10]+aux[11];
      float m = t1/(float)DM;
      aux[12]=m; aux[13]=rsqrtf(t2/(float)DM - m*m + 1e-5f);
    }
    __syncthreads();
    sp[d] = (v-aux[12])*aux[13]*nw[d]+nb[d];
    __syncthreads();
    if (d < NC_*16){
      int c = d>>4, q = d&15;
      float acc = 0.f;
      #pragma unroll
      for (int k=0;k<16;k++) acc = fmaf(sp[q*16+k], clw[(size_t)c*DM+q*16+k], acc);
      cpart[c*16+q] = acc;
    }
    __syncthreads();
    if (d < NC_){
      float acc = clb[d];
      #pragma unroll
      for (int q=0;q<16;q++) acc += cpart[d*16+q];
      outp[b*NC_+d] = acc;
    }
    __syncthreads();
  }
}

// ===================== FALLBACK multi-kernel path (R6, 477 µs) =====================
__global__ void k_embed(const float* __restrict__ emb, const float* __restrict__ pos,
                        const int* __restrict__ ids, float* __restrict__ h){
  int row = blockIdx.x;
  int t = row & (L_-1);
  int d = threadIdx.x;
  int v = ids[row];
  h[(size_t)row*DM + d] = emb[(size_t)v*DM + d] + pos[(size_t)t*DM + d];
}

__global__ void k_cvt2(const float* __restrict__ a, int na, const float* __restrict__ b2,
                       ushort_t* __restrict__ oa, ushort_t* __restrict__ ob, int ntot){
  int i = (blockIdx.x*256 + threadIdx.x)*4;
  if (i >= ntot) return;
  const float* src; ushort_t* dst; int k;
  if (i < na){ src = a; dst = oa; k = i; }
  else       { src = b2; dst = ob; k = i - na; }
  float4 v = *reinterpret_cast<const float4*>(&src[k]);
  ushort4 r;
  r.x = f2bf(v.x); r.y = f2bf(v.y); r.z = f2bf(v.z); r.w = f2bf(v.w);
  *reinterpret_cast<ushort4*>(&dst[k]) = r;
}

__global__ __launch_bounds__(256) void k_gemm_ln(const float* __restrict__ h,
    const ushort_t* __restrict__ W, const float* __restrict__ lw,
    const float* __restrict__ lb, ushort_t* __restrict__ xzb){
  __shared__ ushort_t As[64][264];
  __shared__ ushort_t Ws[64][264];
  int bm = blockIdx.y<<6, bn = blockIdx.x<<6;
  int tid = threadIdx.x;
  {
    int r = tid>>2, q = tid&3;
    const float* src = &h[(size_t)(bm+r)*DM + q*64];
    float4 v[16]; float s1=0.f, s2=0.f;
    #pragma unroll
    for (int i=0;i<16;i++){
      v[i] = *reinterpret_cast<const float4*>(src + i*4);
      s1 += v[i].x+v[i].y+v[i].z+v[i].w;
      s2 += v[i].x*v[i].x+v[i].y*v[i].y+v[i].z*v[i].z+v[i].w*v[i].w;
    }
    s1 += __shfl_xor(s1,1); s2 += __shfl_xor(s2,1);
    s1 += __shfl_xor(s1,2); s2 += __shfl_xor(s2,2);
    float mean = s1*(1.f/DM);
    float rstd = rsqrtf(s2*(1.f/DM) - mean*mean + 1e-5f);
    #pragma unroll
    for (int i=0;i<16;i++){
      int c = q*64 + i*4;
      ushort4 o;
      o.x = f2bf((v[i].x-mean)*rstd*lw[c+0]+lb[c+0]);
      o.y = f2bf((v[i].y-mean)*rstd*lw[c+1]+lb[c+1]);
      o.z = f2bf((v[i].z-mean)*rstd*lw[c+2]+lb[c+2]);
      o.w = f2bf((v[i].w-mean)*rstd*lw[c+3]+lb[c+3]);
      *reinterpret_cast<ushort4*>(&As[r][c]) = o;
    }
    const ushort_t* ws = &W[(size_t)(bn+r)*DM + q*64];
    #pragma unroll
    for (int i=0;i<8;i++)
      *reinterpret_cast<u16x8*>(&Ws[r][q*64+i*8]) = *reinterpret_cast<const u16x8*>(ws + i*8);
  }
  __syncthreads();
  int lane = tid&63, wid = tid>>6;
  int wm = (wid>>1)<<5, wn = (wid&1)<<5;
  int fr = lane&15, fk = (lane>>4)<<3;
  f32x4 acc[2][2] = {};
  #pragma unroll
  for (int k0=0;k0<DM;k0+=32){
    s16x8 a0 = *reinterpret_cast<const s16x8*>(&As[wm+fr][k0+fk]);
    s16x8 a1 = *reinterpret_cast<const s16x8*>(&As[wm+16+fr][k0+fk]);
    s16x8 b0 = *reinterpret_cast<const s16x8*>(&Ws[wn+fr][k0+fk]);
    s16x8 b1 = *reinterpret_cast<const s16x8*>(&Ws[wn+16+fr][k0+fk]);
    acc[0][0] = __builtin_amdgcn_mfma_f32_16x16x32_bf16(a0,b0,acc[0][0],0,0,0);
    acc[0][1] = __builtin_amdgcn_mfma_f32_16x16x32_bf16(a0,b1,acc[0][1],0,0,0);
    acc[1][0] = __builtin_amdgcn_mfma_f32_16x16x32_bf16(a1,b0,acc[1][0],0,0,0);
    acc[1][1] = __builtin_amdgcn_mfma_f32_16x16x32_bf16(a1,b1,acc[1][1],0,0,0);
  }
  int cr = (lane>>4)<<2, cc = lane&15;
  #pragma unroll
  for (int i=0;i<2;i++)
    #pragma unroll
    for (int j=0;j<2;j++){
      int row = bm + wm + (i<<4) + cr;
      int col = bn + wn + (j<<4) + cc;
      #pragma unroll
      for (int r=0;r<4;r++)
        xzb[(size_t)(row+r)*(2*DI_) + col] = f2bf(acc[i][j][r]);
    }
}

__global__ __launch_bounds__(256) void k_xpc(const ushort_t* __restrict__ xzb,
    const float* __restrict__ cw, const float* __restrict__ cb,
    const float* __restrict__ xw, const float* __restrict__ dtw,
    const float* __restrict__ dtb, ushort_t* __restrict__ xcb,
    float* __restrict__ xdbl, ushort_t* __restrict__ deltab){
  __shared__ float sxz[7][DI_];
  __shared__ float sx[4][DI_+16];
  __shared__ float sdbl[4][48];
  int tid = threadIdx.x;
  int m0 = blockIdx.x*4;
  #pragma unroll
  for (int q=0;q<2;q++){
    int idx = q*256 + tid;
    if (idx < 448){
      int i = idx>>6, c8 = (idx&63)<<3;
      int mr = m0 - 3 + i;
      if (mr >= 0){
        u16x8 v = *reinterpret_cast<const u16x8*>(&xzb[(size_t)mr*(2*DI_) + c8]);
        #pragma unroll
        for (int e=0;e<8;e++) sxz[i][c8+e] = bf2f((ushort_t)v[e]);
      } else {
        #pragma unroll
        for (int e=0;e<8;e++) sxz[i][c8+e] = 0.f;
      }
    }
  }
  __syncthreads();
  {
    int r = tid>>6, c8 = (tid&63)<<3;
    int t = (m0 + r) & (L_-1);
    u16x8 outv;
    #pragma unroll
    for (int e=0;e<8;e++){
      int d = c8 + e;
      float acc = cb[d];
      #pragma unroll
      for (int k=0;k<4;k++)
        if (t-3+k >= 0) acc = fmaf(cw[d*4+k], sxz[r+k][d], acc);
      float sv = acc * sigmoidf_(acc);
      sx[r][kidx(d)] = sv;
      outv[e] = (short)f2bf(sv);
    }
    *reinterpret_cast<u16x8*>(&xcb[(size_t)(m0+r)*DI_ + c8]) = outv;
  }
  __syncthreads();
  if (tid < 192){
    int o = tid>>2, q = tid&3;
    const float* wp = &xw[(size_t)o*DI_ + q*128];
    const int qb = q*132;
    float a0=0.f,a1=0.f,a2=0.f,a3=0.f;
    #pragma unroll 8
    for (int k4=0;k4<32;k4++){
      float4 wv = *reinterpret_cast<const float4*>(wp + k4*4);
      int kk = qb + k4*4;
      float4 x0 = *reinterpret_cast<const float4*>(&sx[0][kk]);
      float4 x1 = *reinterpret_cast<const float4*>(&sx[1][kk]);
      float4 x2 = *reinterpret_cast<const float4*>(&sx[2][kk]);
      float4 x3 = *reinterpret_cast<const float4*>(&sx[3][kk]);
      a0 = fmaf(x0.x,wv.x,a0); a0 = fmaf(x0.y,wv.y,a0); a0 = fmaf(x0.z,wv.z,a0); a0 = fmaf(x0.w,wv.w,a0);
      a1 = fmaf(x1.x,wv.x,a1); a1 = fmaf(x1.y,wv.y,a1); a1 = fmaf(x1.z,wv.z,a1); a1 = fmaf(x1.w,wv.w,a1);
      a2 = fmaf(x2.x,wv.x,a2); a2 = fmaf(x2.y,wv.y,a2); a2 = fmaf(x2.z,wv.z,a2); a2 = fmaf(x2.w,wv.w,a2);
      a3 = fmaf(x3.x,wv.x,a3); a3 = fmaf(x3.y,wv.y,a3); a3 = fmaf(x3.z,wv.z,a3); a3 = fmaf(x3.w,wv.w,a3);
    }
    a0 += __shfl_xor(a0,1); a0 += __shfl_xor(a0,2);
    a1 += __shfl_xor(a1,1); a1 += __shfl_xor(a1,2);
    a2 += __shfl_xor(a2,1); a2 += __shfl_xor(a2,2);
    a3 += __shfl_xor(a3,1); a3 += __shfl_xor(a3,2);
    if (q==0){
      sdbl[0][o]=a0; sdbl[1][o]=a1; sdbl[2][o]=a2; sdbl[3][o]=a3;
      xdbl[(size_t)(m0+0)*48+o]=a0;
      xdbl[(size_t)(m0+1)*48+o]=a1;
      xdbl[(size_t)(m0+2)*48+o]=a2;
      xdbl[(size_t)(m0+3)*48+o]=a3;
    }
  }
  __syncthreads();
  #pragma unroll
  for (int idx=0; idx<8; ++idx){
    int flat = idx*256 + tid;
    int r = flat>>9, n = flat&511;
    const float4* wp = reinterpret_cast<const float4*>(&dtw[n*16]);
    float4 w0=wp[0], w1=wp[1], w2=wp[2], w3=wp[3];
    const float* sd = sdbl[r];
    float acc = dtb[n];
    acc = fmaf(sd[0],w0.x,acc);  acc = fmaf(sd[1],w0.y,acc);
    acc = fmaf(sd[2],w0.z,acc);  acc = fmaf(sd[3],w0.w,acc);
    acc = fmaf(sd[4],w1.x,acc);  acc = fmaf(sd[5],w1.y,acc);
    acc = fmaf(sd[6],w1.z,acc);  acc = fmaf(sd[7],w1.w,acc);
    acc = fmaf(sd[8],w2.x,acc);  acc = fmaf(sd[9],w2.y,acc);
    acc = fmaf(sd[10],w2.z,acc); acc = fmaf(sd[11],w2.w,acc);
    acc = fmaf(sd[12],w3.x,acc); acc = fmaf(sd[13],w3.y,acc);
    acc = fmaf(sd[14],w3.z,acc); acc = fmaf(sd[15],w3.w,acc);
    float sp2 = (acc>20.f)? acc : log1pf(__expf(acc));
    deltab[(size_t)(m0+r)*DI_ + n] = f2bf(sp2);
  }
}

__global__ __launch_bounds__(256) void k_scanA(const ushort_t* __restrict__ deltab,
    const ushort_t* __restrict__ xcb, const float* __restrict__ xdbl,
    const float* __restrict__ A_log, float4* __restrict__ smry){
  int j = blockIdx.x, g = blockIdx.y, b = blockIdx.z;
  int tid = threadIdx.x;
  int n = tid&15, dg = tid>>4;
  int d0 = g*16;
  __shared__ float sdel[LC][16], sxv[LC][16], sB[LC][16];
  if (tid < 128){
    int arr = tid>>6, slot = tid&63, row = slot>>1, half = slot&1;
    int m = b*L_ + j*LC + row;
    const ushort_t* src = arr ? xcb : deltab;
    u16x8 v = *reinterpret_cast<const u16x8*>(&src[(size_t)m*DI_ + d0 + half*8]);
    float* dst = arr ? &sxv[row][half*8] : &sdel[row][half*8];
    #pragma unroll
    for (int i=0;i<8;i++) dst[i] = bf2f((ushort_t)v[i]);
  } else {
    int slot = tid-128;
    int row = slot>>2, c4 = (slot&3)<<2;
    int m = b*L_ + j*LC + row;
    *reinterpret_cast<float4*>(&sB[row][c4]) =
      *reinterpret_cast<const float4*>(&xdbl[(size_t)m*48 + 16 + c4]);
  }
  __syncthreads();
  float a = -__expf(A_log[(d0+dg)*DS_ + n]);
  float hs=0.f, hh=0.f, cp=1.f;
  #pragma unroll
  for (int tt=0; tt<LC; tt+=8){
    float dA8[8], dBu8[8];
    #pragma unroll
    for (int t=0;t<8;t++){
      float dv = sdel[tt+t][dg];
      dA8[t]  = __expf(dv*a);
      dBu8[t] = dv * sxv[tt+t][dg] * sB[tt+t][n];
    }
    #pragma unroll
    for (int t=0;t<8;t++){
      float mix = fmaf(ALPHA_, hs-hh, hh);
      hs = fmaf(dA8[t], hs, dBu8[t]);
      hh = fmaf(dA8[t], mix, dBu8[t]);
      cp *= dA8[t];
    }
  }
  smry[(size_t)j*NCHAIN + (size_t)(b*DI_+d0)*DS_ + tid] = float4{cp,hs,hh,0.f};
}

__global__ __launch_bounds__(256) void k_scanC(const ushort_t* __restrict__ deltab,
    const ushort_t* __restrict__ xcb, const float* __restrict__ xdbl,
    const ushort_t* __restrict__ xzb, const float* __restrict__ A_log,
    const float* __restrict__ Dp, const float4* __restrict__ smry,
    ushort_t* __restrict__ y2b){
  int j = blockIdx.x, g = blockIdx.y, b = blockIdx.z;
  int tid = threadIdx.x;
  int n = tid&15, dg = tid>>4;
  int d0 = g*16;
  __shared__ float sdel[LC][16], sxv[LC][16], sB[LC][16], sC[LC][16], sz[LC][16], sy[LC][16];
  if (tid < 128){
    int arr = tid>>6, slot = tid&63, row = slot>>1, half = slot&1;
    int m = b*L_ + j*LC + row;
    const ushort_t* src = arr ? xcb : deltab;
    u16x8 v = *reinterpret_cast<const u16x8*>(&src[(size_t)m*DI_ + d0 + half*8]);
    float* dst = arr ? &sxv[row][half*8] : &sdel[row][half*8];
    #pragma unroll
    for (int i=0;i<8;i++) dst[i] = bf2f((ushort_t)v[i]);
  } else if (tid < 192){
    int slot = tid-128, row = slot>>1, half = slot&1;
    int m = b*L_ + j*LC + row;
    u16x8 v = *reinterpret_cast<const u16x8*>(&xzb[(size_t)m*(2*DI_) + DI_ + d0 + half*8]);
    #pragma unroll
    for (int i=0;i<8;i++) sz[row][half*8+i] = bf2f((ushort_t)v[i]);
  } else {
    int slot = tid-192;
    #pragma unroll
    for (int k=0;k<4;k++){
      int t4 = slot + k*64;
      int arr = t4>>7, idx4 = t4&127;
      int row = idx4>>2, c4 = (idx4&3)<<2;
      int m = b*L_ + j*LC + row;
      float* dst = arr ? &sC[row][c4] : &sB[row][c4];
      *reinterpret_cast<float4*>(dst) =
        *reinterpret_cast<const float4*>(&xdbl[(size_t)m*48 + 16 + arr*16 + c4]);
    }
  }
  int chain = (b*DI_+d0)*DS_ + tid;
  float hs=0.f, hh=0.f;
  #pragma unroll 4
  for (int jj=0; jj<j; ++jj){
    float4 v = smry[(size_t)jj*NCHAIN + chain];
    float snew = fmaf(v.x, hs, v.y);
    hh = fmaf(v.x, fmaf(BETA_LC, hh-hs, hs), v.z);
    hs = snew;
  }
  __syncthreads();
  float a = -__expf(A_log[(d0+dg)*DS_ + n]);
  #pragma unroll
  for (int tt=0; tt<LC; tt+=8){
    float dA8[8], dBu8[8], yv8[8];
    #pragma unroll
    for (int t=0;t<8;t++){
      float dv = sdel[tt+t][dg];
      dA8[t]  = __expf(dv*a);
      dBu8[t] = dv * sxv[tt+t][dg] * sB[tt+t][n];
    }
    #pragma unroll
    for (int t=0;t<8;t++){
      float mix = fmaf(ALPHA_, hs-hh, hh);
      hs = fmaf(dA8[t], hs, dBu8[t]);
      hh = fmaf(dA8[t], mix, dBu8[t]);
      yv8[t] = hh * sC[tt+t][n];
    }
    #pragma unroll
    for (int t=0;t<8;t++){
      yv8[t] += __shfl_xor(yv8[t],1,16);
      yv8[t] += __shfl_xor(yv8[t],2,16);
      yv8[t] += __shfl_xor(yv8[t],4,16);
      yv8[t] += __shfl_xor(yv8[t],8,16);
    }
    if (n==0){
      #pragma unroll
      for (int t=0;t<8;t++) sy[tt+t][dg] = yv8[t];
    }
  }
  __syncthreads();
  float dpv = Dp[d0 + (tid&15)];
  #pragma unroll
  for (int idx=0; idx<2; ++idx){
    int flat = idx*256 + tid;
    int t2 = flat>>4, dd = flat&15;
    float xvv = sxv[t2][dd];
    float zv  = sz [t2][dd];
    float yfin = (sy[t2][dd] + dpv*xvv) * (zv*sigmoidf_(zv));
    y2b[(size_t)(b*L_ + j*LC + t2)*DI_ + d0 + dd] = f2bf(yfin);
  }
}

__global__ __launch_bounds__(256) void k_gemm_out(const ushort_t* __restrict__ A,
    const ushort_t* __restrict__ W, float* __restrict__ h){
  __shared__ ushort_t As[32][264];
  __shared__ ushort_t Ws[64][264];
  int bm = blockIdx.y<<5, bn = blockIdx.x<<6;
  int tid = threadIdx.x;
  int lane = tid&63, wid = tid>>6;
  int wm = (wid>>1)<<4, wn = (wid&1)<<5;
  int fr = lane&15, fk = (lane>>4)<<3;
  f32x4 acc[2] = {};
  for (int k0=0;k0<DI_;k0+=256){
    {
      int r = tid>>3, q = tid&7;
      const ushort_t* src = &A[(size_t)(bm+r)*DI_ + k0 + q*32];
      #pragma unroll
      for (int i=0;i<4;i++)
        *reinterpret_cast<u16x8*>(&As[r][q*32+i*8]) = *reinterpret_cast<const u16x8*>(src+i*8);
      int r2 = tid>>2, q2 = tid&3;
      const ushort_t* ws = &W[(size_t)(bn+r2)*DI_ + k0 + q2*64];
      #pragma unroll
      for (int i=0;i<8;i++)
        *reinterpret_cast<u16x8*>(&Ws[r2][q2*64+i*8]) = *reinterpret_cast<const u16x8*>(ws+i*8);
    }
    __syncthreads();
    #pragma unroll
    for (int k=0;k<256;k+=32){
      s16x8 a0 = *reinterpret_cast<const s16x8*>(&As[wm+fr][k+fk]);
      s16x8 b0 = *reinterpret_cast<const s16x8*>(&Ws[wn+fr][k+fk]);
      s16x8 b1 = *reinterpret_cast<const s16x8*>(&Ws[wn+16+fr][k+fk]);
      acc[0] = __builtin_amdgcn_mfma_f32_16x16x32_bf16(a0,b0,acc[0],0,0,0);
      acc[1] = __builtin_amdgcn_mfma_f32_16x16x32_bf16(a0,b1,acc[1],0,0,0);
    }
    __syncthreads();
  }
  int cr = (lane>>4)<<2, cc = lane&15;
  #pragma unroll
  for (int jj=0;jj<2;jj++){
    int row = bm + wm + cr;
    int col = bn + wn + (jj<<4) + cc;
    #pragma unroll
    for (int r=0;r<4;r++){
      size_t idx2 = (size_t)(row+r)*DM + col;
      h[idx2] += acc[jj][r];
    }
  }
}

__global__ __launch_bounds__(256) void k_pool(const float* __restrict__ h,
    const int* __restrict__ mask, float* __restrict__ partial){
  int p = blockIdx.x, b = blockIdx.y, d = threadIdx.x;
  int t0 = p*64;
  __shared__ float sm[64];
  if (d < 64) sm[d] = (float)mask[b*L_ + t0 + d];
  __syncthreads();
  const float* hp = &h[(size_t)(b*L_ + t0)*DM + d];
  float s = 0.f;
  #pragma unroll 8
  for (int i=0;i<64;i++)
    s = fmaf(sm[i], hp[(size_t)i*DM], s);
  partial[(size_t)(b*16+p)*DM + d] = s;
}

__global__ __launch_bounds__(256) void k_head(const float* __restrict__ partial,
    const int* __restrict__ mask, const float* __restrict__ nw, const float* __restrict__ nb,
    const float* __restrict__ cw, const float* __restrict__ cb, float* __restrict__ out){
  int b = blockIdx.x, d = threadIdx.x;
  int4 mi = *reinterpret_cast<const int4*>(&mask[b*L_ + d*4]);
  float cnt = (float)(mi.x + mi.y + mi.z + mi.w);
  #pragma unroll
  for (int o=32;o>0;o>>=1) cnt += __shfl_down(cnt,o);
  __shared__ float ac[4];
  __shared__ float scnt;
  int wid = d>>6, lane = d&63;
  if (lane==0) ac[wid] = cnt;
  __syncthreads();
  if (d==0) scnt = ac[0]+ac[1]+ac[2]+ac[3];
  __syncthreads();
  float s = 0.f;
  #pragma unroll
  for (int p=0;p<16;p++) s += partial[(size_t)(b*16+p)*DM + d];
  float v = s / scnt;
  float s1 = v, s2 = v*v;
  #pragma unroll
  for (int o=32;o>0;o>>=1){ s1 += __shfl_down(s1,o); s2 += __shfl_down(s2,o); }
  __shared__ float a1[4], a2[4];
  __shared__ float mv[2];
  if (lane==0){ a1[wid]=s1; a2[wid]=s2; }
  __syncthreads();
  if (d==0){
    float t1=a1[0]+a1[1]+a1[2]+a1[3];
    float t2=a2[0]+a2[1]+a2[2]+a2[3];
    float m = t1/(float)DM;
    mv[0]=m; mv[1]=rsqrtf(t2/(float)DM - m*m + 1e-5f);
  }
  __syncthreads();
  __shared__ float sp[DM];
  sp[d] = (v-mv[0])*mv[1]*nw[d]+nb[d];
  __syncthreads();
  __shared__ float cpart[NC_][16];
  if (d < NC_*16){
    int c = d>>4, q = d&15;
    float acc = 0.f;
    #pragma unroll
    for (int k=0;k<16;k++) acc = fmaf(sp[q*16+k], cw[(size_t)c*DM+q*16+k], acc);
    cpart[c][q] = acc;
  }
  __syncthreads();
  if (d < NC_){
    float acc = cb[d];
    #pragma unroll
    for (int q=0;q<16;q++) acc += cpart[d][q];
    out[b*NC_+d] = acc;
  }
}

extern "C" void kernel_launch(void* const* d_in, const int* in_sizes, int n_in,
                              void* d_out, int out_size, void* d_ws, size_t ws_size,
                              hipStream_t stream){
  const float* emb   = (const float*)d_in[0];
  const float* pos   = (const float*)d_in[1];
  const float* ln_w  = (const float*)d_in[2];
  const float* ln_b  = (const float*)d_in[3];
  const float* ipw   = (const float*)d_in[4];
  const float* cw    = (const float*)d_in[5];
  const float* cb    = (const float*)d_in[6];
  const float* xpw   = (const float*)d_in[7];
  const float* dtw   = (const float*)d_in[8];
  const float* dtb   = (const float*)d_in[9];
  const float* A_log = (const float*)d_in[10];
  const float* Dp    = (const float*)d_in[11];
  const float* opw   = (const float*)d_in[12];
  const float* nw    = (const float*)d_in[13];
  const float* nb    = (const float*)d_in[14];
  const float* clw   = (const float*)d_in[15];
  const float* clb   = (const float*)d_in[16];
  const int*   ids   = (const int*)d_in[17];
  const int*   mask  = (const int*)d_in[18];
  float* out = (float*)d_out;

  float* ws    = (float*)d_ws;
  float* h     = ws;                      // 524288
  float* xdbl  = h + 524288;              // 98304
  float* part  = xdbl + 98304;            // 8192
  float4* smry = (float4*)(part + 8192);  // 524288 float4
  float2* initA= (float2*)((float*)smry + 2097152); // 524288 float2
  ushort_t* xzb    = (ushort_t*)((float*)initA + 1048576); // 2048*1024
  ushort_t* xcb    = xzb + 2097152;       // 2048*512
  ushort_t* deltab = xcb + 1048576;       // 2048*512
  ushort_t* y2b    = deltab + 1048576;    // 2048*512
  ushort_t* ipwb   = y2b + 1048576;       // 6*1024*256
  ushort_t* opwb   = ipwb + 1572864;      // 6*256*512

  // ---- try cooperative single-kernel path ----
  bool done = false;
  int dev = 0;
  (void)hipGetDevice(&dev);
  int coop = 0;
  (void)hipDeviceGetAttribute(&coop, hipDeviceAttributeCooperativeLaunch, dev);
  int occ = 0;
  (void)hipOccupancyMaxActiveBlocksPerMultiprocessor(&occ, k_net, 256, 0);
  if (coop && occ > 0){
    int grid = occ * 256;
    if (grid > 1024) grid = 1024;
    void* args[] = {
      (void*)&emb, (void*)&pos, (void*)&ids, (void*)&mask,
      (void*)&ln_w, (void*)&ln_b, (void*)&ipw, (void*)&opw,
      (void*)&cw, (void*)&cb, (void*)&xpw, (void*)&dtw, (void*)&dtb,
      (void*)&A_log, (void*)&Dp, (void*)&nw, (void*)&nb, (void*)&clw, (void*)&clb,
      (void*)&out,
      (void*)&h, (void*)&xdbl, (void*)&part, (void*)&smry, (void*)&initA,
      (void*)&xzb, (void*)&xcb, (void*)&y2b, (void*)&ipwb, (void*)&opwb
    };
    hipError_t err = hipLaunchCooperativeKernel((void*)k_net, dim3(grid), dim3(256),
                                                args, 0, stream);
    if (err == hipSuccess) done = true;
    else (void)hipGetLastError();   // clear error, fall back
  }

  if (!done){
    // ---- fallback: proven R6 multi-kernel path ----
    const int NA = 6*2*DI_*DM, NB = 6*DM*DI_;
    k_cvt2<<<dim3((NA+NB)/1024), 256, 0, stream>>>(ipw, NA, opw, ipwb, opwb, NA+NB);
    k_embed<<<dim3(B_*L_), dim3(DM), 0, stream>>>(emb, pos, ids, h);
    for (int l=0; l<NL_; ++l){
      k_gemm_ln<<<dim3(16, 32), 256, 0, stream>>>(
          h, ipwb + (size_t)l*2*DI_*DM, ln_w + l*DM, ln_b + l*DM, xzb);
      k_xpc<<<dim3((B_*L_)/4), 256, 0, stream>>>(
          xzb, cw + l*DI_*4, cb + l*DI_, xpw + (size_t)l*48*DI_,
          dtw + (size_t)l*DI_*16, dtb + l*DI_, xcb, xdbl, deltab);
      k_scanA<<<dim3(NCH, DI_/16, B_), 256, 0, stream>>>(
          deltab, xcb, xdbl, A_log + (size_t)l*DI_*DS_, smry);
      k_scanC<<<dim3(NCH, DI_/16, B_), 256, 0, stream>>>(
          deltab, xcb, xdbl, xzb, A_log + (size_t)l*DI_*DS_, Dp + l*DI_,
          smry, y2b);
      k_gemm_out<<<dim3(DM/64, (B_*L_)/32), 256, 0, stream>>>(
          y2b, opwb + (size_t)l*DM*DI_, h);
    }
    k_pool<<<dim3(16, B_), 256, 0, stream>>>(h, mask, part);
    k_head<<<dim3(B_), 256, 0, stream>>>(part, mask, nw, nb, clw, clb, out);
  }
}

// Round 12
// 483.846 us; speedup vs baseline: 5.1827x; 3.8668x over previous
//
#include <hip/hip_runtime.h>
#include <math.h>

#define B_ 2
#define L_ 1024
#define DM 256
#define NL_ 6
#define DI_ 512
#define DS_ 16
#define DC_ 4
#define NC_ 10
#define ALPHA_ 0.1f
#define LC 32
#define NCH (L_/LC)            // 32 chunks
#define NCHAIN (B_*DI_*DS_)    // 16384 chains
#define BETA_LC 0.034336838202925124f  // 0.9^32

typedef unsigned short ushort_t;
typedef __attribute__((ext_vector_type(8))) short s16x8;      // 8 bf16 (MFMA A/B frag)
typedef __attribute__((ext_vector_type(4))) float f32x4;      // MFMA C/D frag
typedef __attribute__((ext_vector_type(8))) unsigned short u16x8;

__device__ __forceinline__ float sigmoidf_(float x){ return 1.f/(1.f+__expf(-x)); }
__device__ __forceinline__ ushort_t f2bf(float f){
  union{float f;unsigned u;} c; c.f=f; unsigned u=c.u;
  return (ushort_t)((u + 0x7fffu + ((u>>16)&1u))>>16);
}
__device__ __forceinline__ float bf2f(ushort_t h){
  union{unsigned u;float f;} c; c.u = ((unsigned)h)<<16; return c.f;
}
// stagger-pad index for sx: insert 4-word gap every 128 words (bank-conflict fix)
__device__ __forceinline__ int kidx(int d){ return d + ((d>>7)<<2); }

// ---------------- embed ----------------
__global__ void k_embed(const float* __restrict__ emb, const float* __restrict__ pos,
                        const int* __restrict__ ids, float* __restrict__ h){
  int row = blockIdx.x;
  int t = row & (L_-1);
  int d = threadIdx.x;
  int v = ids[row];
  h[(size_t)row*DM + d] = emb[(size_t)v*DM + d] + pos[(size_t)t*DM + d];
}

// ---------------- fp32 -> bf16 weight conversion (both weight sets, one launch) ----------------
__global__ void k_cvt2(const float* __restrict__ a, int na, const float* __restrict__ b2,
                       ushort_t* __restrict__ oa, ushort_t* __restrict__ ob, int ntot){
  int i = (blockIdx.x*256 + threadIdx.x)*4;
  if (i >= ntot) return;
  const float* src; ushort_t* dst; int k;
  if (i < na){ src = a; dst = oa; k = i; }
  else       { src = b2; dst = ob; k = i - na; }
  float4 v = *reinterpret_cast<const float4*>(&src[k]);
  ushort4 r;
  r.x = f2bf(v.x); r.y = f2bf(v.y); r.z = f2bf(v.z); r.w = f2bf(v.w);
  *reinterpret_cast<ushort4*>(&dst[k]) = r;
}

// ---------------- fused LN + in_proj GEMM (bf16 MFMA), writes xz bf16 ----------------
__global__ __launch_bounds__(256) void k_gemm_ln(const float* __restrict__ h,
    const ushort_t* __restrict__ W, const float* __restrict__ lw,
    const float* __restrict__ lb, ushort_t* __restrict__ xzb){
  __shared__ ushort_t As[64][264];
  __shared__ ushort_t Ws[64][264];
  int bm = blockIdx.y<<6, bn = blockIdx.x<<6;
  int tid = threadIdx.x;
  {
    int r = tid>>2, q = tid&3;
    const float* src = &h[(size_t)(bm+r)*DM + q*64];
    float4 v[16]; float s1=0.f, s2=0.f;
    #pragma unroll
    for (int i=0;i<16;i++){
      v[i] = *reinterpret_cast<const float4*>(src + i*4);
      s1 += v[i].x+v[i].y+v[i].z+v[i].w;
      s2 += v[i].x*v[i].x+v[i].y*v[i].y+v[i].z*v[i].z+v[i].w*v[i].w;
    }
    s1 += __shfl_xor(s1,1); s2 += __shfl_xor(s2,1);
    s1 += __shfl_xor(s1,2); s2 += __shfl_xor(s2,2);
    float mean = s1*(1.f/DM);
    float rstd = rsqrtf(s2*(1.f/DM) - mean*mean + 1e-5f);
    #pragma unroll
    for (int i=0;i<16;i++){
      int c = q*64 + i*4;
      ushort4 o;
      o.x = f2bf((v[i].x-mean)*rstd*lw[c+0]+lb[c+0]);
      o.y = f2bf((v[i].y-mean)*rstd*lw[c+1]+lb[c+1]);
      o.z = f2bf((v[i].z-mean)*rstd*lw[c+2]+lb[c+2]);
      o.w = f2bf((v[i].w-mean)*rstd*lw[c+3]+lb[c+3]);
      *reinterpret_cast<ushort4*>(&As[r][c]) = o;
    }
    const ushort_t* ws = &W[(size_t)(bn+r)*DM + q*64];
    #pragma unroll
    for (int i=0;i<8;i++)
      *reinterpret_cast<u16x8*>(&Ws[r][q*64+i*8]) = *reinterpret_cast<const u16x8*>(ws + i*8);
  }
  __syncthreads();
  int lane = tid&63, wid = tid>>6;
  int wm = (wid>>1)<<5, wn = (wid&1)<<5;
  int fr = lane&15, fk = (lane>>4)<<3;
  f32x4 acc[2][2] = {};
  #pragma unroll
  for (int k0=0;k0<DM;k0+=32){
    s16x8 a0 = *reinterpret_cast<const s16x8*>(&As[wm+fr][k0+fk]);
    s16x8 a1 = *reinterpret_cast<const s16x8*>(&As[wm+16+fr][k0+fk]);
    s16x8 b0 = *reinterpret_cast<const s16x8*>(&Ws[wn+fr][k0+fk]);
    s16x8 b1 = *reinterpret_cast<const s16x8*>(&Ws[wn+16+fr][k0+fk]);
    acc[0][0] = __builtin_amdgcn_mfma_f32_16x16x32_bf16(a0,b0,acc[0][0],0,0,0);
    acc[0][1] = __builtin_amdgcn_mfma_f32_16x16x32_bf16(a0,b1,acc[0][1],0,0,0);
    acc[1][0] = __builtin_amdgcn_mfma_f32_16x16x32_bf16(a1,b0,acc[1][0],0,0,0);
    acc[1][1] = __builtin_amdgcn_mfma_f32_16x16x32_bf16(a1,b1,acc[1][1],0,0,0);
  }
  int cr = (lane>>4)<<2, cc = lane&15;
  #pragma unroll
  for (int i=0;i<2;i++)
    #pragma unroll
    for (int j=0;j<2;j++){
      int row = bm + wm + (i<<4) + cr;
      int col = bn + wn + (j<<4) + cc;
      #pragma unroll
      for (int r=0;r<4;r++)
        xzb[(size_t)(row+r)*(2*DI_) + col] = f2bf(acc[i][j][r]);
    }
}

// ---------------- fused conv+SiLU + x_proj + dt_proj + softplus (4 rows/block) ----------------
// writes xc (bf16), xdbl (fp32), delta (bf16)
__global__ __launch_bounds__(256) void k_xpc(const ushort_t* __restrict__ xzb,
    const float* __restrict__ cw, const float* __restrict__ cb,
    const float* __restrict__ xw, const float* __restrict__ dtw,
    const float* __restrict__ dtb, ushort_t* __restrict__ xcb,
    float* __restrict__ xdbl, ushort_t* __restrict__ deltab){
  __shared__ float sxz[7][DI_];
  __shared__ float sx[4][DI_+16];    // stagger-padded: kidx(d)
  __shared__ float sdbl[4][48];
  int tid = threadIdx.x;
  int m0 = blockIdx.x*4;
  // stage x-half of xz rows m0-3..m0+3 (448 u16x8 tasks)
  #pragma unroll
  for (int q=0;q<2;q++){
    int idx = q*256 + tid;
    if (idx < 448){
      int i = idx>>6, c8 = (idx&63)<<3;
      int mr = m0 - 3 + i;
      if (mr >= 0){
        u16x8 v = *reinterpret_cast<const u16x8*>(&xzb[(size_t)mr*(2*DI_) + c8]);
        #pragma unroll
        for (int e=0;e<8;e++) sxz[i][c8+e] = bf2f((ushort_t)v[e]);
      } else {
        #pragma unroll
        for (int e=0;e<8;e++) sxz[i][c8+e] = 0.f;
      }
    }
  }
  __syncthreads();
  // conv + SiLU: 256 tasks of 8 d each
  {
    int r = tid>>6, c8 = (tid&63)<<3;
    int t = (m0 + r) & (L_-1);
    u16x8 outv;
    #pragma unroll
    for (int e=0;e<8;e++){
      int d = c8 + e;
      float acc = cb[d];
      #pragma unroll
      for (int k=0;k<4;k++)
        if (t-3+k >= 0) acc = fmaf(cw[d*4+k], sxz[r+k][d], acc);
      float sv = acc * sigmoidf_(acc);
      sx[r][kidx(d)] = sv;
      outv[e] = (short)f2bf(sv);
    }
    *reinterpret_cast<u16x8*>(&xcb[(size_t)(m0+r)*DI_ + c8]) = outv;
  }
  __syncthreads();
  // x_proj: 48 outputs x 4 rows
  if (tid < 192){
    int o = tid>>2, q = tid&3;
    const float* wp = &xw[(size_t)o*DI_ + q*128];
    const int qb = q*132;
    float a0=0.f,a1=0.f,a2=0.f,a3=0.f;
    #pragma unroll 8
    for (int k4=0;k4<32;k4++){
      float4 wv = *reinterpret_cast<const float4*>(wp + k4*4);
      int kk = qb + k4*4;
      float4 x0 = *reinterpret_cast<const float4*>(&sx[0][kk]);
      float4 x1 = *reinterpret_cast<const float4*>(&sx[1][kk]);
      float4 x2 = *reinterpret_cast<const float4*>(&sx[2][kk]);
      float4 x3 = *reinterpret_cast<const float4*>(&sx[3][kk]);
      a0 = fmaf(x0.x,wv.x,a0); a0 = fmaf(x0.y,wv.y,a0); a0 = fmaf(x0.z,wv.z,a0); a0 = fmaf(x0.w,wv.w,a0);
      a1 = fmaf(x1.x,wv.x,a1); a1 = fmaf(x1.y,wv.y,a1); a1 = fmaf(x1.z,wv.z,a1); a1 = fmaf(x1.w,wv.w,a1);
      a2 = fmaf(x2.x,wv.x,a2); a2 = fmaf(x2.y,wv.y,a2); a2 = fmaf(x2.z,wv.z,a2); a2 = fmaf(x2.w,wv.w,a2);
      a3 = fmaf(x3.x,wv.x,a3); a3 = fmaf(x3.y,wv.y,a3); a3 = fmaf(x3.z,wv.z,a3); a3 = fmaf(x3.w,wv.w,a3);
    }
    a0 += __shfl_xor(a0,1); a0 += __shfl_xor(a0,2);
    a1 += __shfl_xor(a1,1); a1 += __shfl_xor(a1,2);
    a2 += __shfl_xor(a2,1); a2 += __shfl_xor(a2,2);
    a3 += __shfl_xor(a3,1); a3 += __shfl_xor(a3,2);
    if (q==0){
      sdbl[0][o]=a0; sdbl[1][o]=a1; sdbl[2][o]=a2; sdbl[3][o]=a3;
      xdbl[(size_t)(m0+0)*48+o]=a0;
      xdbl[(size_t)(m0+1)*48+o]=a1;
      xdbl[(size_t)(m0+2)*48+o]=a2;
      xdbl[(size_t)(m0+3)*48+o]=a3;
    }
  }
  __syncthreads();
  #pragma unroll
  for (int idx=0; idx<8; ++idx){
    int flat = idx*256 + tid;
    int r = flat>>9, n = flat&511;
    const float4* wp = reinterpret_cast<const float4*>(&dtw[n*16]);
    float4 w0=wp[0], w1=wp[1], w2=wp[2], w3=wp[3];
    const float* sd = sdbl[r];
    float acc = dtb[n];
    acc = fmaf(sd[0],w0.x,acc);  acc = fmaf(sd[1],w0.y,acc);
    acc = fmaf(sd[2],w0.z,acc);  acc = fmaf(sd[3],w0.w,acc);
    acc = fmaf(sd[4],w1.x,acc);  acc = fmaf(sd[5],w1.y,acc);
    acc = fmaf(sd[6],w1.z,acc);  acc = fmaf(sd[7],w1.w,acc);
    acc = fmaf(sd[8],w2.x,acc);  acc = fmaf(sd[9],w2.y,acc);
    acc = fmaf(sd[10],w2.z,acc); acc = fmaf(sd[11],w2.w,acc);
    acc = fmaf(sd[12],w3.x,acc); acc = fmaf(sd[13],w3.y,acc);
    acc = fmaf(sd[14],w3.z,acc); acc = fmaf(sd[15],w3.w,acc);
    float sp2 = (acc>20.f)? acc : log1pf(__expf(acc));
    deltab[(size_t)(m0+r)*DI_ + n] = f2bf(sp2);
  }
}

// ================= chunked parallel scan (LC=32) =================
// Pass A: per-chunk summary {cp, hs_loc, hh_loc} packed in float4
__global__ __launch_bounds__(256) void k_scanA(const ushort_t* __restrict__ deltab,
    const ushort_t* __restrict__ xcb, const float* __restrict__ xdbl,
    const float* __restrict__ A_log, float4* __restrict__ smry){
  int j = blockIdx.x, g = blockIdx.y, b = blockIdx.z;
  int tid = threadIdx.x;
  int n = tid&15, dg = tid>>4;
  int d0 = g*16;
  __shared__ float sdel[LC][16], sxv[LC][16], sB[LC][16];
  if (tid < 128){
    int arr = tid>>6, slot = tid&63, row = slot>>1, half = slot&1;
    int m = b*L_ + j*LC + row;
    const ushort_t* src = arr ? xcb : deltab;
    u16x8 v = *reinterpret_cast<const u16x8*>(&src[(size_t)m*DI_ + d0 + half*8]);
    float* dst = arr ? &sxv[row][half*8] : &sdel[row][half*8];
    #pragma unroll
    for (int i=0;i<8;i++) dst[i] = bf2f((ushort_t)v[i]);
  } else {
    int slot = tid-128;                 // 128 float4 tasks for sB
    int row = slot>>2, c4 = (slot&3)<<2;
    int m = b*L_ + j*LC + row;
    *reinterpret_cast<float4*>(&sB[row][c4]) =
      *reinterpret_cast<const float4*>(&xdbl[(size_t)m*48 + 16 + c4]);
  }
  __syncthreads();
  float a = -__expf(A_log[(d0+dg)*DS_ + n]);
  float hs=0.f, hh=0.f, cp=1.f;
  #pragma unroll
  for (int tt=0; tt<LC; tt+=8){
    float dA8[8], dBu8[8];
    #pragma unroll
    for (int t=0;t<8;t++){
      float dv = sdel[tt+t][dg];
      dA8[t]  = __expf(dv*a);
      dBu8[t] = dv * sxv[tt+t][dg] * sB[tt+t][n];
    }
    #pragma unroll
    for (int t=0;t<8;t++){
      float mix = fmaf(ALPHA_, hs-hh, hh);
      hs = fmaf(dA8[t], hs, dBu8[t]);
      hh = fmaf(dA8[t], mix, dBu8[t]);
      cp *= dA8[t];
    }
  }
  smry[(size_t)j*NCHAIN + (size_t)(b*DI_+d0)*DS_ + tid] = float4{cp,hs,hh,0.f};
}

// Pass C: inline lookback + re-run + gate, writes y2 bf16
__global__ __launch_bounds__(256) void k_scanC(const ushort_t* __restrict__ deltab,
    const ushort_t* __restrict__ xcb, const float* __restrict__ xdbl,
    const ushort_t* __restrict__ xzb, const float* __restrict__ A_log,
    const float* __restrict__ Dp, const float4* __restrict__ smry,
    ushort_t* __restrict__ y2b){
  int j = blockIdx.x, g = blockIdx.y, b = blockIdx.z;
  int tid = threadIdx.x;
  int n = tid&15, dg = tid>>4;
  int d0 = g*16;
  __shared__ float sdel[LC][16], sxv[LC][16], sB[LC][16], sC[LC][16], sz[LC][16], sy[LC][16];
  if (tid < 128){
    int arr = tid>>6, slot = tid&63, row = slot>>1, half = slot&1;
    int m = b*L_ + j*LC + row;
    const ushort_t* src = arr ? xcb : deltab;
    u16x8 v = *reinterpret_cast<const u16x8*>(&src[(size_t)m*DI_ + d0 + half*8]);
    float* dst = arr ? &sxv[row][half*8] : &sdel[row][half*8];
    #pragma unroll
    for (int i=0;i<8;i++) dst[i] = bf2f((ushort_t)v[i]);
  } else if (tid < 192){
    int slot = tid-128, row = slot>>1, half = slot&1;
    int m = b*L_ + j*LC + row;
    u16x8 v = *reinterpret_cast<const u16x8*>(&xzb[(size_t)m*(2*DI_) + DI_ + d0 + half*8]);
    #pragma unroll
    for (int i=0;i<8;i++) sz[row][half*8+i] = bf2f((ushort_t)v[i]);
  } else {
    int slot = tid-192;                 // 64 threads x 4 float4 tasks for sB+sC
    #pragma unroll
    for (int k=0;k<4;k++){
      int t4 = slot + k*64;             // 256 tasks: 2 arrays x 128 float4
      int arr = t4>>7, idx4 = t4&127;
      int row = idx4>>2, c4 = (idx4&3)<<2;
      int m = b*L_ + j*LC + row;
      float* dst = arr ? &sC[row][c4] : &sB[row][c4];
      *reinterpret_cast<float4*>(dst) =
        *reinterpret_cast<const float4*>(&xdbl[(size_t)m*48 + 16 + arr*16 + c4]);
    }
  }
  // inline lookback over chunks 0..j-1 (one float4 load per step)
  int chain = (b*DI_+d0)*DS_ + tid;
  float hs=0.f, hh=0.f;
  #pragma unroll 4
  for (int jj=0; jj<j; ++jj){
    float4 v = smry[(size_t)jj*NCHAIN + chain];
    float snew = fmaf(v.x, hs, v.y);
    hh = fmaf(v.x, fmaf(BETA_LC, hh-hs, hs), v.z);
    hs = snew;
  }
  __syncthreads();
  float a = -__expf(A_log[(d0+dg)*DS_ + n]);
  #pragma unroll
  for (int tt=0; tt<LC; tt+=8){
    float dA8[8], dBu8[8], yv8[8];
    #pragma unroll
    for (int t=0;t<8;t++){
      float dv = sdel[tt+t][dg];
      dA8[t]  = __expf(dv*a);
      dBu8[t] = dv * sxv[tt+t][dg] * sB[tt+t][n];
    }
    #pragma unroll
    for (int t=0;t<8;t++){
      float mix = fmaf(ALPHA_, hs-hh, hh);
      hs = fmaf(dA8[t], hs, dBu8[t]);
      hh = fmaf(dA8[t], mix, dBu8[t]);
      yv8[t] = hh * sC[tt+t][n];
    }
    #pragma unroll
    for (int t=0;t<8;t++){
      yv8[t] += __shfl_xor(yv8[t],1,16);
      yv8[t] += __shfl_xor(yv8[t],2,16);
      yv8[t] += __shfl_xor(yv8[t],4,16);
      yv8[t] += __shfl_xor(yv8[t],8,16);
    }
    if (n==0){
      #pragma unroll
      for (int t=0;t<8;t++) sy[tt+t][dg] = yv8[t];
    }
  }
  __syncthreads();
  float dpv = Dp[d0 + (tid&15)];
  #pragma unroll
  for (int idx=0; idx<2; ++idx){
    int flat = idx*256 + tid;
    int t2 = flat>>4, dd = flat&15;
    float xvv = sxv[t2][dd];
    float zv  = sz [t2][dd];
    float yfin = (sy[t2][dd] + dpv*xvv) * (zv*sigmoidf_(zv));
    y2b[(size_t)(b*L_ + j*LC + t2)*DI_ + d0 + dd] = f2bf(yfin);
  }
}

// ---------------- out_proj GEMM (bf16 MFMA) + residual, h += y2 @ W^T ----------------
__global__ __launch_bounds__(256) void k_gemm_out(const ushort_t* __restrict__ A,
    const ushort_t* __restrict__ W, float* __restrict__ h){
  __shared__ ushort_t As[32][264];
  __shared__ ushort_t Ws[64][264];
  int bm = blockIdx.y<<5, bn = blockIdx.x<<6;
  int tid = threadIdx.x;
  int lane = tid&63, wid = tid>>6;
  int wm = (wid>>1)<<4, wn = (wid&1)<<5;
  int fr = lane&15, fk = (lane>>4)<<3;
  f32x4 acc[2] = {};
  for (int k0=0;k0<DI_;k0+=256){
    {
      int r = tid>>3, q = tid&7;
      const ushort_t* src = &A[(size_t)(bm+r)*DI_ + k0 + q*32];
      #pragma unroll
      for (int i=0;i<4;i++)
        *reinterpret_cast<u16x8*>(&As[r][q*32+i*8]) = *reinterpret_cast<const u16x8*>(src+i*8);
      int r2 = tid>>2, q2 = tid&3;
      const ushort_t* ws = &W[(size_t)(bn+r2)*DI_ + k0 + q2*64];
      #pragma unroll
      for (int i=0;i<8;i++)
        *reinterpret_cast<u16x8*>(&Ws[r2][q2*64+i*8]) = *reinterpret_cast<const u16x8*>(ws+i*8);
    }
    __syncthreads();
    #pragma unroll
    for (int k=0;k<256;k+=32){
      s16x8 a0 = *reinterpret_cast<const s16x8*>(&As[wm+fr][k+fk]);
      s16x8 b0 = *reinterpret_cast<const s16x8*>(&Ws[wn+fr][k+fk]);
      s16x8 b1 = *reinterpret_cast<const s16x8*>(&Ws[wn+16+fr][k+fk]);
      acc[0] = __builtin_amdgcn_mfma_f32_16x16x32_bf16(a0,b0,acc[0],0,0,0);
      acc[1] = __builtin_amdgcn_mfma_f32_16x16x32_bf16(a0,b1,acc[1],0,0,0);
    }
    __syncthreads();
  }
  int cr = (lane>>4)<<2, cc = lane&15;
  #pragma unroll
  for (int jj=0;jj<2;jj++){
    int row = bm + wm + cr;
    int col = bn + wn + (jj<<4) + cc;
    #pragma unroll
    for (int r=0;r<4;r++){
      size_t idx2 = (size_t)(row+r)*DM + col;
      h[idx2] += acc[jj][r];
    }
  }
}

// ---------------- masked pooling: 32 blocks, LDS-staged mask ----------------
__global__ __launch_bounds__(256) void k_pool(const float* __restrict__ h,
    const int* __restrict__ mask, float* __restrict__ partial){
  int p = blockIdx.x, b = blockIdx.y, d = threadIdx.x;
  int t0 = p*64;
  __shared__ float sm[64];
  if (d < 64) sm[d] = (float)mask[b*L_ + t0 + d];
  __syncthreads();
  const float* hp = &h[(size_t)(b*L_ + t0)*DM + d];
  float s = 0.f;
  #pragma unroll 8
  for (int i=0;i<64;i++)
    s = fmaf(sm[i], hp[(size_t)i*DM], s);
  partial[(size_t)(b*16+p)*DM + d] = s;
}

// ---------------- final: count + LN + classifier (1 block/batch) ----------------
__global__ __launch_bounds__(256) void k_head(const float* __restrict__ partial,
    const int* __restrict__ mask, const float* __restrict__ nw, const float* __restrict__ nb,
    const float* __restrict__ cw, const float* __restrict__ cb, float* __restrict__ out){
  int b = blockIdx.x, d = threadIdx.x;
  int4 mi = *reinterpret_cast<const int4*>(&mask[b*L_ + d*4]);
  float cnt = (float)(mi.x + mi.y + mi.z + mi.w);
  #pragma unroll
  for (int o=32;o>0;o>>=1) cnt += __shfl_down(cnt,o);
  __shared__ float ac[4];
  __shared__ float scnt;
  int wid = d>>6, lane = d&63;
  if (lane==0) ac[wid] = cnt;
  __syncthreads();
  if (d==0) scnt = ac[0]+ac[1]+ac[2]+ac[3];
  __syncthreads();
  float s = 0.f;
  #pragma unroll
  for (int p=0;p<16;p++) s += partial[(size_t)(b*16+p)*DM + d];
  float v = s / scnt;
  float s1 = v, s2 = v*v;
  #pragma unroll
  for (int o=32;o>0;o>>=1){ s1 += __shfl_down(s1,o); s2 += __shfl_down(s2,o); }
  __shared__ float a1[4], a2[4];
  __shared__ float mv[2];
  if (lane==0){ a1[wid]=s1; a2[wid]=s2; }
  __syncthreads();
  if (d==0){
    float t1=a1[0]+a1[1]+a1[2]+a1[3];
    float t2=a2[0]+a2[1]+a2[2]+a2[3];
    float m = t1/(float)DM;
    mv[0]=m; mv[1]=rsqrtf(t2/(float)DM - m*m + 1e-5f);
  }
  __syncthreads();
  __shared__ float sp[DM];
  sp[d] = (v-mv[0])*mv[1]*nw[d]+nb[d];
  __syncthreads();
  __shared__ float cpart[NC_][16];
  if (d < NC_*16){
    int c = d>>4, q = d&15;
    float acc = 0.f;
    #pragma unroll
    for (int k=0;k<16;k++) acc = fmaf(sp[q*16+k], cw[(size_t)c*DM+q*16+k], acc);
    cpart[c][q] = acc;
  }
  __syncthreads();
  if (d < NC_){
    float acc = cb[d];
    #pragma unroll
    for (int q=0;q<16;q++) acc += cpart[d][q];
    out[b*NC_+d] = acc;
  }
}

extern "C" void kernel_launch(void* const* d_in, const int* in_sizes, int n_in,
                              void* d_out, int out_size, void* d_ws, size_t ws_size,
                              hipStream_t stream){
  const float* emb   = (const float*)d_in[0];
  const float* pos   = (const float*)d_in[1];
  const float* ln_w  = (const float*)d_in[2];
  const float* ln_b  = (const float*)d_in[3];
  const float* ipw   = (const float*)d_in[4];
  const float* cw    = (const float*)d_in[5];
  const float* cb    = (const float*)d_in[6];
  const float* xpw   = (const float*)d_in[7];
  const float* dtw   = (const float*)d_in[8];
  const float* dtb   = (const float*)d_in[9];
  const float* A_log = (const float*)d_in[10];
  const float* Dp    = (const float*)d_in[11];
  const float* opw   = (const float*)d_in[12];
  const float* nw    = (const float*)d_in[13];
  const float* nb    = (const float*)d_in[14];
  const float* clw   = (const float*)d_in[15];
  const float* clb   = (const float*)d_in[16];
  const int*   ids   = (const int*)d_in[17];
  const int*   mask  = (const int*)d_in[18];
  float* out = (float*)d_out;

  float* ws    = (float*)d_ws;
  float* h     = ws;                     // 524288 floats
  float* xdbl  = h + 524288;             // 98304
  float* part  = xdbl + 98304;           // 8192
  float4* smry = (float4*)(part + 8192); // 524288 float4 = 2097152 floats
  ushort_t* xzb    = (ushort_t*)((float*)smry + 2097152); // 2048*1024 bf16
  ushort_t* xcb    = xzb + 2097152;      // 2048*512 bf16
  ushort_t* deltab = xcb + 1048576;      // 2048*512 bf16
  ushort_t* y2b    = deltab + 1048576;   // 2048*512 bf16
  ushort_t* ipwb   = y2b + 1048576;      // 6*1024*256 bf16
  ushort_t* opwb   = ipwb + 1572864;     // 6*256*512 bf16

  const int NA = 6*2*DI_*DM, NB = 6*DM*DI_;
  k_cvt2<<<dim3((NA+NB)/1024), 256, 0, stream>>>(ipw, NA, opw, ipwb, opwb, NA+NB);
  k_embed<<<dim3(B_*L_), dim3(DM), 0, stream>>>(emb, pos, ids, h);

  for (int l=0; l<NL_; ++l){
    k_gemm_ln<<<dim3(16, 32), 256, 0, stream>>>(
        h, ipwb + (size_t)l*2*DI_*DM, ln_w + l*DM, ln_b + l*DM, xzb);
    k_xpc<<<dim3((B_*L_)/4), 256, 0, stream>>>(
        xzb, cw + l*DI_*DC_, cb + l*DI_, xpw + (size_t)l*48*DI_,
        dtw + (size_t)l*DI_*16, dtb + l*DI_, xcb, xdbl, deltab);
    k_scanA<<<dim3(NCH, DI_/16, B_), 256, 0, stream>>>(
        deltab, xcb, xdbl, A_log + (size_t)l*DI_*DS_, smry);
    k_scanC<<<dim3(NCH, DI_/16, B_), 256, 0, stream>>>(
        deltab, xcb, xdbl, xzb, A_log + (size_t)l*DI_*DS_, Dp + l*DI_,
        smry, y2b);
    k_gemm_out<<<dim3(DM/64, (B_*L_)/32), 256, 0, stream>>>(
        y2b, opwb + (size_t)l*DM*DI_, h);
  }
  k_pool<<<dim3(16, B_), 256, 0, stream>>>(h, mask, part);
  k_head<<<dim3(B_), 256, 0, stream>>>(part, mask, nw, nb, clw, clb, out);
}